// Round 16
// baseline (606.227 us; speedup 1.0000x reference)
//
#include <hip/hip_runtime.h>

// Problem constants
#define T_SEQ 2048
#define D_EMB 2048
#define NHEAD 16
#define HS    128
#define NVOC  32000

typedef __attribute__((ext_vector_type(8))) short bf16x8;
typedef __attribute__((ext_vector_type(4))) float f32x4;
typedef unsigned short bfu;   // bf16 bits

__device__ __forceinline__ f32x4 mfma16(bf16x8 a, bf16x8 b, f32x4 c) {
    return __builtin_amdgcn_mfma_f32_16x16x32_bf16(a, b, c, 0, 0, 0);
}

// fp32 -> bf16 RNE
__device__ __forceinline__ bfu f2bu(float f) {
    unsigned int u = __float_as_uint(f);
    unsigned int r = (u + 0x7fffu + ((u >> 16) & 1u)) >> 16;
    return (bfu)r;
}
__device__ __forceinline__ float b2f(bfu r) {
    return __uint_as_float((unsigned int)r << 16);
}

// async global->LDS, 16B per lane; lds base must be wave-uniform (HW adds lane*16)
__device__ __forceinline__ void async_copy16(void* lds, const void* g) {
    __builtin_amdgcn_global_load_lds(
        (const __attribute__((address_space(1))) unsigned int*)g,
        (__attribute__((address_space(3))) unsigned int*)lds, 16, 0, 0);
}

#define SB0 __builtin_amdgcn_sched_barrier(0)
#define BARRIER __builtin_amdgcn_s_barrier()
#define WAIT_VM8   asm volatile("s_waitcnt vmcnt(8)" ::: "memory")
#define WAIT_VM6   asm volatile("s_waitcnt vmcnt(6)" ::: "memory")
#define WAIT_VM4   asm volatile("s_waitcnt vmcnt(4)" ::: "memory")
#define WAIT_VM2   asm volatile("s_waitcnt vmcnt(2)" ::: "memory")
#define WAIT_VM0   asm volatile("s_waitcnt vmcnt(0)" ::: "memory")

// ---------------------------------------------------------------------------
// k_prep: embed + projw/Wqkv transposes.
// Blocks: [0,1024) projw, [1024,4096) Wq/Wk/Wv, [4096,6144) embed.
// ---------------------------------------------------------------------------
__device__ __forceinline__ void job_t64(const float* __restrict__ in,
                                        bfu* __restrict__ out, int R, int C,
                                        float scale, int tx, int ty, char* lds) {
    float (*tile)[65] = (float(*)[65])lds;
    const int r0 = ty * 64, c0 = tx * 64;
    const int t = threadIdx.x;
#pragma unroll
    for (int it = 0; it < 4; ++it) {
        int fi = it * 256 + t;
        int row = fi >> 4, c4 = (fi & 15) * 4;
        float4 v = *(const float4*)(in + (size_t)(r0 + row) * C + c0 + c4);
        tile[row][c4]     = v.x; tile[row][c4 + 1] = v.y;
        tile[row][c4 + 2] = v.z; tile[row][c4 + 3] = v.w;
    }
    __syncthreads();
#pragma unroll
    for (int it = 0; it < 4; ++it) {
        int ci = it * 256 + t;
        int oc = ci >> 4, r4 = (ci & 15) * 4;
        ushort4 u;
        u.x = f2bu(tile[r4 + 0][oc] * scale);
        u.y = f2bu(tile[r4 + 1][oc] * scale);
        u.z = f2bu(tile[r4 + 2][oc] * scale);
        u.w = f2bu(tile[r4 + 3][oc] * scale);
        *(ushort4*)(out + (size_t)(c0 + oc) * R + r0 + r4) = u;
    }
}

__global__ __launch_bounds__(256)
void k_prep(const int* __restrict__ ids, const float* __restrict__ we,
            const float* __restrict__ pe, bfu* __restrict__ xb,
            const float* __restrict__ Wq, const float* __restrict__ Wk,
            const float* __restrict__ Wv, const float* __restrict__ projw,
            bfu* __restrict__ WqT, bfu* __restrict__ WkT, bfu* __restrict__ WvT,
            bfu* __restrict__ projT, float qscale) {
    __shared__ __align__(16) char lds[64 * 65 * 4];
    int b = blockIdx.x;
    if (b < 1024) {
        job_t64(projw, projT, D_EMB, D_EMB, 1.0f, b & 31, b >> 5, lds);
    } else if (b < 4096) {
        int bb = b - 1024;
        int which = bb >> 10;            // 0=Wq 1=Wk 2=Wv
        bb &= 1023;
        int z = bb >> 6, rem = bb & 63;
        size_t zo = (size_t)z * D_EMB * HS;
        const float* in = (which == 0) ? Wq : (which == 1) ? Wk : Wv;
        bfu* out = (which == 0) ? WqT : (which == 1) ? WkT : WvT;
        job_t64(in + zo, out + zo, D_EMB, HS, (which == 0) ? qscale : 1.0f,
                rem & 1, rem >> 1, lds);
    } else {
        int tt = b - 4096;
        const int row = ids[tt];
        const float4* wr = (const float4*)(we + (size_t)row * D_EMB);
        const float4* pr = (const float4*)(pe + (size_t)tt * D_EMB);
        bfu* xbr = xb + (size_t)tt * D_EMB;
        int i = threadIdx.x;
#pragma unroll
        for (int r = 0; r < 2; ++r, i += 256) {
            float4 a = wr[i], p = pr[i];
            ushort4 u;
            u.x = f2bu(a.x + p.x); u.y = f2bu(a.y + p.y);
            u.z = f2bu(a.z + p.z); u.w = f2bu(a.w + p.w);
            *(ushort4*)(xbr + i * 4) = u;
        }
    }
}

// ---------------------------------------------------------------------------
// bf16 transpose: in [rows][stride] -> out [cols][Tout].  Used for V -> V^T.
// ---------------------------------------------------------------------------
__global__ void k_transpose_bf(const bfu* __restrict__ in, bfu* __restrict__ out,
                               int stride, int Tout) {
    __shared__ bfu tile[64][72];
    const int r0 = blockIdx.x * 64;
    const int c0 = blockIdx.y * 64;
    const int t = threadIdx.x;
#pragma unroll
    for (int it = 0; it < 2; ++it) {
        int idx = it * 256 + t;
        int row = idx >> 3, c8 = (idx & 7) * 8;
        *(bf16x8*)&tile[row][c8] = *(const bf16x8*)(in + (size_t)(r0 + row) * stride + c0 + c8);
    }
    __syncthreads();
#pragma unroll
    for (int it = 0; it < 2; ++it) {
        int idx = it * 256 + t;
        int oc = idx >> 3, r8 = (idx & 7) * 8;
        bf16x8 v;
#pragma unroll
        for (int j = 0; j < 8; ++j) v[j] = (short)tile[r8 + j][oc];
        *(bf16x8*)(out + (size_t)(c0 + oc) * Tout + r0 + r8) = v;
    }
}

// ---------------------------------------------------------------------------
// GEMM (m97-style 128x128), involution swizzle.  EPI 1 = bf16 + bias + resid.
// ---------------------------------------------------------------------------
template <int EPI>
__global__ __launch_bounds__(256, 2)
void k_gemm_nt(const bfu* __restrict__ A, const bfu* __restrict__ Bt,
               bfu* __restrict__ Cv, const float* __restrict__ bias,
               const bfu* __restrict__ resb, int M, int N, int K) {
    __shared__ __align__(16) char smem[2 * 128 * 64 * 2];
    const int tid = threadIdx.x;
    const int w = tid >> 6, lane = tid & 63;
    const int wr = w >> 1, wc = w & 1;
    const int lr = lane & 15, lk = lane >> 4;
    const int sw = ((lk ^ (lr & 7)) << 4);
    const int mb = M >> 7;
    const int m0 = (blockIdx.x % mb) << 7;
    const int n0 = (blockIdx.x / mb) << 7;
    char* As = smem;
    char* Bs = smem + 16384;
    f32x4 acc[4][4];
#pragma unroll
    for (int i = 0; i < 4; ++i)
#pragma unroll
        for (int j = 0; j < 4; ++j) acc[i][j] = (f32x4){0.f, 0.f, 0.f, 0.f};

    const bfu* Ag = A + (size_t)m0 * K;
    const bfu* Bg = Bt + (size_t)n0 * K;

    for (int kk = 0; kk < K; kk += 64) {
        __syncthreads();
#pragma unroll
        for (int r = 0; r < 4; ++r) {
            int i = r * 256 + tid;
            int row = i >> 3, slot = (i & 7) ^ (row & 7);
            async_copy16(As + (r * 256 + w * 64) * 16,
                         Ag + (size_t)row * K + kk + slot * 8);
        }
#pragma unroll
        for (int r = 0; r < 4; ++r) {
            int i = r * 256 + tid;
            int row = i >> 3, slot = (i & 7) ^ (row & 7);
            async_copy16(Bs + (r * 256 + w * 64) * 16,
                         Bg + (size_t)row * K + kk + slot * 8);
        }
        __syncthreads();
#pragma unroll
        for (int kc = 0; kc < 2; ++kc) {
            const int so = kc ? (sw ^ 64) : sw;
            bf16x8 a[4], b[4];
#pragma unroll
            for (int mf = 0; mf < 4; ++mf)
                a[mf] = *(const bf16x8*)(As + (wr * 64 + mf * 16 + lr) * 128 + so);
#pragma unroll
            for (int nf = 0; nf < 4; ++nf)
                b[nf] = *(const bf16x8*)(Bs + (wc * 64 + nf * 16 + lr) * 128 + so);
#pragma unroll
            for (int mf = 0; mf < 4; ++mf)
#pragma unroll
                for (int nf = 0; nf < 4; ++nf)
                    acc[mf][nf] = mfma16(a[mf], b[nf], acc[mf][nf]);
        }
    }
#pragma unroll
    for (int nf = 0; nf < 4; ++nf) {
        int col = n0 + wc * 64 + nf * 16 + lr;
        float bv = (EPI >= 1) ? bias[col] : 0.0f;
#pragma unroll
        for (int mf = 0; mf < 4; ++mf) {
            int row0 = m0 + wr * 64 + mf * 16 + lk * 4;
            f32x4 v = acc[mf][nf];
#pragma unroll
            for (int j = 0; j < 4; ++j) {
                size_t idx = (size_t)(row0 + j) * N + col;
                float val = v[j] + bv;
                if (EPI == 1) val += b2f(resb[idx]);
                Cv[idx] = f2bu(val);
            }
        }
    }
}

// ---------------------------------------------------------------------------
// 256x256 BK=64 GEMM — round-16 READ-AHEAD schedule (deconfounded r6):
// every ds_read issued one full phase before first MFMA use, on the r11
// relaxed base (no lgkm0 pins, raw barriers, compiler counted-lgkm).
// Reads: P0(t): A1(t) [P1 use]; P1: B1(t) [P2 use]; P3: A0/B0(t+1) [next P0].
// Both aA and bB quadrant-indexed (r6 clobber fix). Stage order unchanged:
// P0:A1(t+1) P1:B1(t+1) P2:B0(t+2) P3:A0(t+2).
// FIFO (traced): prologue 12 issues -> vm6 (A1(0) resident for P0 read);
// steady entry 6 outstanding {B1(t),B0(t+1),A0(t+1)}; waits vm6 at P0/P2/P3
// end, NONE at P1. Tail T=nkt-2: 6,-,4,2 ; nkt-1: 0,-,-,-.
// WAR: each stage's target slot last read >=2 barriers earlier (checked).
// FUSE_FCW: filler blocks run the fcw transpose.
// ---------------------------------------------------------------------------
__device__ __forceinline__ void stage_chunk(char* sm, const bfu* A_, const bfu* B_,
                                            int K, int tt, int kind, int w,
                                            int laneRow, int laneCol) {
    char* base = sm + (size_t)(tt & 1) * 65536 + ((kind >= 2) ? 32768 : 0);
    const bfu* G = (kind >= 2) ? B_ : A_;
#pragma unroll
    for (int r = 0; r < 2; ++r) {
        int p = w * 2 + r;
        int row0 = (kind < 2) ? ((kind & 1) * 64 + (p & 7) * 8 + (p >> 3) * 128)
                              : ((kind & 1) * 32 + (p & 3) * 8 + (p >> 2) * 64);
        const char* g = (const char*)G + ((size_t)(row0 + laneRow) * K + tt * 64) * 2 + laneCol;
        async_copy16(base + row0 * 128, g);
    }
}

template <int Q>
__device__ __forceinline__ void read_A(bf16x8 (&aA)[2][4][2], const char* bufA,
                                       int wm, int lr, int sw0) {
    const char* p = bufA + ((wm * 128 + Q * 64 + lr) * 128);
#pragma unroll
    for (int mf = 0; mf < 4; ++mf) {
        aA[Q][mf][0] = *(const bf16x8*)(p + mf * 2048 + sw0);
        aA[Q][mf][1] = *(const bf16x8*)(p + mf * 2048 + (sw0 ^ 64));
    }
}

template <int Q>
__device__ __forceinline__ void read_B(bf16x8 (&bB)[2][2][2], const char* bufB,
                                       int wn, int lr, int sw0) {
    const char* p = bufB + ((wn * 64 + Q * 32 + lr) * 128);
#pragma unroll
    for (int nf = 0; nf < 2; ++nf) {
        bB[Q][nf][0] = *(const bf16x8*)(p + nf * 2048 + sw0);
        bB[Q][nf][1] = *(const bf16x8*)(p + nf * 2048 + (sw0 ^ 64));
    }
}

template <int QM, int QN>
__device__ __forceinline__ void mfma_quad(f32x4 (&acc)[8][4], bf16x8 (&aA)[2][4][2],
                                          bf16x8 (&bB)[2][2][2]) {
    __builtin_amdgcn_s_setprio(1);
#pragma unroll
    for (int kc = 0; kc < 2; ++kc)
#pragma unroll
        for (int mf = 0; mf < 4; ++mf)
#pragma unroll
            for (int nf = 0; nf < 2; ++nf)
                acc[QM * 4 + mf][QN * 2 + nf] =
                    mfma16(aA[QM][mf][kc], bB[QN][nf][kc], acc[QM * 4 + mf][QN * 2 + nf]);
    __builtin_amdgcn_s_setprio(0);
}

// fcw transpose tile (512 threads): 256 rows x 64 cols, swizzled bf16 LDS.
__device__ __forceinline__ void job_fcw512(const float* __restrict__ in,
                                           bfu* __restrict__ out, int tx, int ty,
                                           char* lds) {
    const int r0 = ty * 256, c0 = tx * 64;
    const int t = threadIdx.x;
#pragma unroll
    for (int it = 0; it < 8; ++it) {
        int fi = it * 512 + t;
        int row = fi >> 4, c4 = (fi & 15) * 4;
        float4 v = *(const float4*)(in + (size_t)(r0 + row) * NVOC + c0 + c4);
        ushort4 u;
        u.x = f2bu(v.x); u.y = f2bu(v.y); u.z = f2bu(v.z); u.w = f2bu(v.w);
        *(ushort4*)(lds + row * 128 + ((c4 * 2) ^ (((row >> 3) & 7) << 4))) = u;
    }
    __syncthreads();
#pragma unroll
    for (int it = 0; it < 4; ++it) {
        int idx = it * 512 + t;
        int oc = idx >> 5, r8 = (idx & 31) * 8;
        bf16x8 v;
#pragma unroll
        for (int j = 0; j < 8; ++j) {
            int row = r8 + j;
            v[j] = (short)*(const bfu*)(lds + row * 128 +
                                        ((oc * 2) ^ (((row >> 3) & 7) << 4)));
        }
        *(bf16x8*)(out + (size_t)(c0 + oc) * D_EMB + r0 + r8) = v;
    }
}

template <int EPI, bool FUSE_FCW>
__global__ __launch_bounds__(512, 2)
void k_gemm256(const bfu* __restrict__ A, const bfu* __restrict__ Bt,
               void* __restrict__ Cv, const float* __restrict__ bias,
               int M, int N, int K,
               const float* __restrict__ fcw, bfu* __restrict__ fcwT,
               int gemm_nwgs) {
    __shared__ __align__(16) char smem[2 * 65536];   // 128 KiB
    if (FUSE_FCW && (int)blockIdx.x >= gemm_nwgs) {
        int fb = blockIdx.x - gemm_nwgs;             // [0, 4000)
        job_fcw512(fcw, fcwT, fb % 500, fb / 500, smem);
        return;
    }
    const int tid = threadIdx.x;
    const int w = tid >> 6, lane = tid & 63;
    const int wm = w >> 2, wn = w & 3;
    const int lr = lane & 15, lk = lane >> 4;
    const int sw0 = ((lk ^ (lr & 7)) << 4);
    const int laneRow = lane >> 3;
    const int laneCol = ((lane & 7) ^ (lane >> 3)) << 4;

    const int mb = M >> 8;
    const int nwgs = mb * (N >> 8);
    int bid = blockIdx.x;
    int swz = ((nwgs & 7) == 0) ? ((bid & 7) * (nwgs >> 3) + (bid >> 3)) : bid;
    const int m0 = (swz % mb) << 8;
    const int n0 = (swz / mb) << 8;

    const bfu* Ag = A + (size_t)m0 * K;
    const bfu* Bg = Bt + (size_t)n0 * K;

    f32x4 acc[8][4];
#pragma unroll
    for (int i = 0; i < 8; ++i)
#pragma unroll
        for (int j = 0; j < 4; ++j) acc[i][j] = (f32x4){0.f, 0.f, 0.f, 0.f};
    bf16x8 aA[2][4][2], bB[2][2][2];

    const int nkt = K >> 6;   // requires nkt >= 3

    // prologue: 12 issues; vm6 retires A0(0),B0(0),A1(0) (A1 resident for P0 read)
    stage_chunk(smem, Ag, Bg, K, 0, 0, w, laneRow, laneCol);
    stage_chunk(smem, Ag, Bg, K, 0, 2, w, laneRow, laneCol);
    stage_chunk(smem, Ag, Bg, K, 0, 1, w, laneRow, laneCol);
    stage_chunk(smem, Ag, Bg, K, 0, 3, w, laneRow, laneCol);
    stage_chunk(smem, Ag, Bg, K, 1, 2, w, laneRow, laneCol);
    stage_chunk(smem, Ag, Bg, K, 1, 0, w, laneRow, laneCol);
    WAIT_VM6; SB0; BARRIER;
    read_A<0>(aA, smem, wm, lr, sw0);
    read_B<0>(bB, smem + 32768, wn, lr, sw0);

    for (int t = 0; t < nkt - 2; ++t) {
        const char* bufA = smem + (size_t)(t & 1) * 65536;
        const char* bufB = bufA + 32768;
        const char* bufAn = smem + (size_t)((t + 1) & 1) * 65536;
        const char* bufBn = bufAn + 32768;
        // P0: read-ahead A1(t); stage A1(t+1); MFMA q00
        read_A<1>(aA, bufA, wm, lr, sw0);
        stage_chunk(smem, Ag, Bg, K, t + 1, 1, w, laneRow, laneCol);
        mfma_quad<0, 0>(acc, aA, bB);
        WAIT_VM6; BARRIER;
        // P1: read-ahead B1(t); stage B1(t+1); MFMA q10
        read_B<1>(bB, bufB, wn, lr, sw0);
        stage_chunk(smem, Ag, Bg, K, t + 1, 3, w, laneRow, laneCol);
        mfma_quad<1, 0>(acc, aA, bB);
        BARRIER;
        // P2: stage B0(t+2); MFMA q01
        stage_chunk(smem, Ag, Bg, K, t + 2, 2, w, laneRow, laneCol);
        mfma_quad<0, 1>(acc, aA, bB);
        WAIT_VM6; BARRIER;
        // P3: read-ahead A0/B0(t+1); stage A0(t+2); MFMA q11
        read_A<0>(aA, bufAn, wm, lr, sw0);
        read_B<0>(bB, bufBn, wn, lr, sw0);
        stage_chunk(smem, Ag, Bg, K, t + 2, 0, w, laneRow, laneCol);
        mfma_quad<1, 1>(acc, aA, bB);
        WAIT_VM6; BARRIER;
    }

    {   // T = nkt-2: stages only A1/B1(nkt-1); waits 6,-,4,2
        const int t = nkt - 2;
        const char* bufA = smem + (size_t)(t & 1) * 65536;
        const char* bufB = bufA + 32768;
        const char* bufAn = smem + (size_t)((t + 1) & 1) * 65536;
        const char* bufBn = bufAn + 32768;
        read_A<1>(aA, bufA, wm, lr, sw0);
        stage_chunk(smem, Ag, Bg, K, t + 1, 1, w, laneRow, laneCol);
        mfma_quad<0, 0>(acc, aA, bB);
        WAIT_VM6; BARRIER;

        read_B<1>(bB, bufB, wn, lr, sw0);
        stage_chunk(smem, Ag, Bg, K, t + 1, 3, w, laneRow, laneCol);
        mfma_quad<1, 0>(acc, aA, bB);
        BARRIER;

        mfma_quad<0, 1>(acc, aA, bB);
        WAIT_VM4; BARRIER;

        read_A<0>(aA, bufAn, wm, lr, sw0);
        read_B<0>(bB, bufBn, wn, lr, sw0);
        mfma_quad<1, 1>(acc, aA, bB);
        WAIT_VM2; BARRIER;
    }
    {   // t = nkt-1: drain
        const int t = nkt - 1;
        const char* bufA = smem + (size_t)(t & 1) * 65536;
        const char* bufB = bufA + 32768;
        read_A<1>(aA, bufA, wm, lr, sw0);
        mfma_quad<0, 0>(acc, aA, bB);
        WAIT_VM0; BARRIER;

        read_B<1>(bB, bufB, wn, lr, sw0);
        mfma_quad<1, 0>(acc, aA, bB);
        mfma_quad<0, 1>(acc, aA, bB);
        mfma_quad<1, 1>(acc, aA, bB);
    }

#pragma unroll
    for (int nfg = 0; nfg < 4; ++nfg) {
        int col = n0 + wn * 64 + nfg * 16 + lr;
        float bv = (EPI == 2) ? bias[col] : 0.0f;
#pragma unroll
        for (int mfg = 0; mfg < 8; ++mfg) {
            int row0 = m0 + wm * 128 + mfg * 16 + lk * 4;
            f32x4 v = acc[mfg][nfg];
#pragma unroll
            for (int j = 0; j < 4; ++j) {
                size_t idx = (size_t)(row0 + j) * N + col;
                if (EPI == 2) ((float*)Cv)[idx] = v[j] + bv;
                else          ((bfu*)Cv)[idx] = f2bu(v[j]);
            }
        }
    }
}

// ---------------------------------------------------------------------------
// Flash attention (causal), r12 version (LDS-staged K/V, verified).
// ---------------------------------------------------------------------------
__global__ __launch_bounds__(256, 2)
void k_attn(const bfu* __restrict__ q, const bfu* __restrict__ k,
            const bfu* __restrict__ vT, bfu* __restrict__ o, int qks) {
    __shared__ __align__(16) char kvlds[2][32768];   // [buf][K 16KB | V 16KB]
    __shared__ __align__(16) bfu plds[4][16][72];
    const int w = threadIdx.x >> 6, lane = threadIdx.x & 63;
    const int lr = lane & 15, lk = lane >> 4;
    const int h = blockIdx.y;
    const int bxr = (gridDim.x - 1) - blockIdx.x;   // heavy blocks first
    const int qrow = bxr * 64 + w * 16;
    const int sw = ((lk ^ (lr & 7)) << 4);

    const int krow = lane >> 4, kslot = lane & 15;
    const int vrow = lane >> 3, vslot = lane & 7;

    bf16x8 aq[4];
#pragma unroll
    for (int kc = 0; kc < 4; ++kc)
        aq[kc] = *(const bf16x8*)(q + (size_t)(qrow + lr) * qks + h * HS + kc * 32 + lk * 8);

    f32x4 O[8];
#pragma unroll
    for (int hf = 0; hf < 8; ++hf) O[hf] = (f32x4){0.f, 0.f, 0.f, 0.f};
    float m_[4], l_[4];
#pragma unroll
    for (int j = 0; j < 4; ++j) { m_[j] = -__builtin_inff(); l_[j] = 0.f; }

    const int nst = bxr + 1;

#define STAGE_KV(st)                                                            \
    {                                                                           \
        char* bK = kvlds[(st) & 1];                                             \
        char* bV = bK + 16384;                                                  \
        const int s0_ = (st) * 64;                                              \
        _Pragma("unroll")                                                       \
        for (int j = 0; j < 4; ++j) {                                           \
            int ir = w * 4 + j;                                                 \
            int krw = ir * 4 + krow;                                            \
            int kss = (kslot & 8) | ((kslot & 7) ^ (krw & 7));                  \
            async_copy16(bK + ir * 1024,                                        \
                         k + (size_t)(s0_ + krw) * qks + h * HS + kss * 8);     \
            int vrw = ir * 8 + vrow;                                            \
            int vss = vslot ^ (vrw & 7);                                        \
            async_copy16(bV + ir * 1024,                                        \
                         vT + (size_t)(h * HS + vrw) * T_SEQ + s0_ + vss * 8);  \
        }                                                                       \
    }

    STAGE_KV(0);
    WAIT_VM0; BARRIER;

    for (int st = 0; st < nst; ++st) {
        const char* bK = kvlds[st & 1];
        const char* bV = bK + 16384;
        const int s0 = st * 64;
        if (st + 1 < nst) STAGE_KV(st + 1);

        f32x4 S[4];
#pragma unroll
        for (int nf = 0; nf < 4; ++nf) S[nf] = (f32x4){0.f, 0.f, 0.f, 0.f};
#pragma unroll
        for (int nf = 0; nf < 4; ++nf) {
            const char* kp = bK + (nf * 16 + lr) * 256;
#pragma unroll
            for (int kc = 0; kc < 4; ++kc) {
                bf16x8 bk = *(const bf16x8*)(kp + ((kc & 2) << 6) + (sw ^ ((kc & 1) << 6)));
                S[nf] = mfma16(aq[kc], bk, S[nf]);
            }
        }
        if (s0 + 63 > qrow) {
#pragma unroll
            for (int nf = 0; nf < 4; ++nf) {
                int scol = s0 + nf * 16 + lr;
#pragma unroll
                for (int j = 0; j < 4; ++j)
                    if (scol > qrow + lk * 4 + j) S[nf][j] = -1e30f;
            }
        }
        float tm[4];
#pragma unroll
        for (int j = 0; j < 4; ++j)
            tm[j] = fmaxf(fmaxf(S[0][j], S[1][j]), fmaxf(S[2][j], S[3][j]));
#pragma unroll
        for (int d = 1; d < 16; d <<= 1)
#pragma unroll
            for (int j = 0; j < 4; ++j) tm[j] = fmaxf(tm[j], __shfl_xor(tm[j], d));
        float mn[4], ts[4];
#pragma unroll
        for (int j = 0; j < 4; ++j) mn[j] = fmaxf(m_[j], tm[j]);
#pragma unroll
        for (int nf = 0; nf < 4; ++nf)
#pragma unroll
            for (int j = 0; j < 4; ++j) S[nf][j] = __expf(S[nf][j] - mn[j]);
#pragma unroll
        for (int j = 0; j < 4; ++j) ts[j] = S[0][j] + S[1][j] + S[2][j] + S[3][j];
#pragma unroll
        for (int d = 1; d < 16; d <<= 1)
#pragma unroll
            for (int j = 0; j < 4; ++j) ts[j] += __shfl_xor(ts[j], d);
#pragma unroll
        for (int nf = 0; nf < 4; ++nf)
#pragma unroll
            for (int j = 0; j < 4; ++j)
                plds[w][lk * 4 + j][nf * 16 + lr] = f2bu(S[nf][j]);
#pragma unroll
        for (int j = 0; j < 4; ++j) {
            float f = __expf(m_[j] - mn[j]);
            l_[j] = l_[j] * f + ts[j];
            m_[j] = mn[j];
#pragma unroll
            for (int hf = 0; hf < 8; ++hf) O[hf][j] *= f;
        }
        bf16x8 pa[2];
#pragma unroll
        for (int kc2 = 0; kc2 < 2; ++kc2)
            pa[kc2] = *(const bf16x8*)(&plds[w][lr][kc2 * 32 + lk * 8]);
#pragma unroll
        for (int hf = 0; hf < 8; ++hf) {
            const char* vp = bV + (hf * 16 + lr) * 128;
#pragma unroll
            for (int kc2 = 0; kc2 < 2; ++kc2) {
                bf16x8 bv = *(const bf16x8*)(vp + (sw ^ (kc2 << 6)));
                O[hf] = mfma16(pa[kc2], bv, O[hf]);
            }
        }
        WAIT_VM0; BARRIER;
    }
#undef STAGE_KV

#pragma unroll
    for (int j = 0; j < 4; ++j) {
        float inv = 1.0f / l_[j];
        size_t rbase = (size_t)(qrow + lk * 4 + j) * D_EMB + h * HS;
#pragma unroll
        for (int hf = 0; hf < 8; ++hf)
            o[rbase + hf * 16 + lr] = f2bu(O[hf][j] * inv);
    }
}

// ---------------------------------------------------------------------------
extern "C" void kernel_launch(void* const* d_in, const int* in_sizes, int n_in,
                              void* d_out, int out_size, void* d_ws, size_t ws_size,
                              hipStream_t stream) {
    const int*   ids   = (const int*)d_in[0];
    const float* we    = (const float*)d_in[1];
    const float* pe    = (const float*)d_in[2];
    const float* Wq    = (const float*)d_in[3];
    const float* Wk    = (const float*)d_in[4];
    const float* Wv    = (const float*)d_in[5];
    const float* projw = (const float*)d_in[6];
    const float* projb = (const float*)d_in[7];
    const float* fcw   = (const float*)d_in[8];
    const float* fcb   = (const float*)d_in[9];
    float* out = (float*)d_out;
    (void)in_sizes; (void)n_in; (void)out_size; (void)ws_size;

    char* ws = (char*)d_ws;
    size_t off = 0;
    bfu*   fcwT  = (bfu*)(ws + off);  off += (size_t)NVOC * D_EMB * 2;       // 131 MB
    bfu*   xb    = (bfu*)(ws + off);  off += (size_t)T_SEQ * D_EMB * 2;
    bfu*   qkvb  = (bfu*)(ws + off);  off += (size_t)T_SEQ * 3 * D_EMB * 2;  // q|k|v [T][6144]
    bfu*   vTb   = (bfu*)(ws + off);  off += (size_t)D_EMB * T_SEQ * 2;
    bfu*   WqT   = (bfu*)(ws + off);  off += (size_t)D_EMB * D_EMB * 2;      // WqT|WkT|WvT contiguous
    bfu*   WkT   = (bfu*)(ws + off);  off += (size_t)D_EMB * D_EMB * 2;
    bfu*   WvT   = (bfu*)(ws + off);  off += (size_t)D_EMB * D_EMB * 2;
    bfu*   projT = (bfu*)(ws + off);  off += (size_t)D_EMB * D_EMB * 2;
    bfu*   attnb = WqT;   // aliased after QKV GEMM
    bfu*   resb  = WvT;

    const float qscale = 0.08838834764831845f;  // 1/sqrt(HS), folded into WqT

    // prep (no fcw): embed + projw + Wq/Wk/Wv transposes
    k_prep<<<6144, 256, 0, stream>>>(ids, we, pe, xb, Wq, Wk, Wv, projw,
                                     WqT, WkT, WvT, projT, qscale);

    // QKV GEMM (192 blocks) + fcw transpose (4000 filler blocks), one launch
    k_gemm256<0, true><<<192 + 4000, 512, 0, stream>>>(
        xb, WqT, qkvb, nullptr, T_SEQ, 3 * D_EMB, D_EMB, fcw, fcwT, 192);

    k_transpose_bf<<<dim3(T_SEQ / 64, D_EMB / 64), 256, 0, stream>>>(
        qkvb + 2 * D_EMB, vTb, 3 * D_EMB, T_SEQ);

    k_attn<<<dim3(T_SEQ / 64, NHEAD), 256, 0, stream>>>(qkvb, qkvb + D_EMB, vTb, attnb, 3 * D_EMB);

    k_gemm_nt<1><<<(T_SEQ / 128) * (D_EMB / 128), 256, 0, stream>>>(
        attnb, projT, resb, projb, xb, T_SEQ, D_EMB, D_EMB);

    // vocab GEMM (read-ahead schedule, f32 out + bias)
    k_gemm256<2, false><<<(T_SEQ / 256) * (NVOC / 256), 512, 0, stream>>>(
        resb, fcwT, out, fcb, T_SEQ, NVOC, D_EMB, nullptr, nullptr, 0);
}

// Round 17
// 563.392 us; speedup vs baseline: 1.0760x; 1.0760x over previous
//
#include <hip/hip_runtime.h>

// Problem constants
#define T_SEQ 2048
#define D_EMB 2048
#define NHEAD 16
#define HS    128
#define NVOC  32000

typedef __attribute__((ext_vector_type(8))) short bf16x8;
typedef __attribute__((ext_vector_type(4))) float f32x4;
typedef unsigned short bfu;   // bf16 bits

__device__ __forceinline__ f32x4 mfma16(bf16x8 a, bf16x8 b, f32x4 c) {
    return __builtin_amdgcn_mfma_f32_16x16x32_bf16(a, b, c, 0, 0, 0);
}

// fp32 -> bf16 RNE
__device__ __forceinline__ bfu f2bu(float f) {
    unsigned int u = __float_as_uint(f);
    unsigned int r = (u + 0x7fffu + ((u >> 16) & 1u)) >> 16;
    return (bfu)r;
}
__device__ __forceinline__ float b2f(bfu r) {
    return __uint_as_float((unsigned int)r << 16);
}

// async global->LDS, 16B per lane; lds base must be wave-uniform (HW adds lane*16)
__device__ __forceinline__ void async_copy16(void* lds, const void* g) {
    __builtin_amdgcn_global_load_lds(
        (const __attribute__((address_space(1))) unsigned int*)g,
        (__attribute__((address_space(3))) unsigned int*)lds, 16, 0, 0);
}

#define SB0 __builtin_amdgcn_sched_barrier(0)
#define BARRIER __builtin_amdgcn_s_barrier()
#define WAIT_VM8   asm volatile("s_waitcnt vmcnt(8)" ::: "memory")
#define WAIT_VM6   asm volatile("s_waitcnt vmcnt(6)" ::: "memory")
#define WAIT_VM4   asm volatile("s_waitcnt vmcnt(4)" ::: "memory")
#define WAIT_VM2   asm volatile("s_waitcnt vmcnt(2)" ::: "memory")
#define WAIT_VM0   asm volatile("s_waitcnt vmcnt(0)" ::: "memory")

// ---------------------------------------------------------------------------
// k_prep: ONE kernel for all preprocessing (r14-verified).
// Blocks: [0,4000) fcw, [4000,5024) projw, [5024,8096) Wq/Wk/Wv, rest embed.
// ---------------------------------------------------------------------------
__device__ __forceinline__ void job_t64(const float* __restrict__ in,
                                        bfu* __restrict__ out, int R, int C,
                                        float scale, int tx, int ty, char* lds) {
    float (*tile)[65] = (float(*)[65])lds;
    const int r0 = ty * 64, c0 = tx * 64;
    const int t = threadIdx.x;
#pragma unroll
    for (int it = 0; it < 4; ++it) {
        int fi = it * 256 + t;
        int row = fi >> 4, c4 = (fi & 15) * 4;
        float4 v = *(const float4*)(in + (size_t)(r0 + row) * C + c0 + c4);
        tile[row][c4]     = v.x; tile[row][c4 + 1] = v.y;
        tile[row][c4 + 2] = v.z; tile[row][c4 + 3] = v.w;
    }
    __syncthreads();
#pragma unroll
    for (int it = 0; it < 4; ++it) {
        int ci = it * 256 + t;
        int oc = ci >> 4, r4 = (ci & 15) * 4;
        ushort4 u;
        u.x = f2bu(tile[r4 + 0][oc] * scale);
        u.y = f2bu(tile[r4 + 1][oc] * scale);
        u.z = f2bu(tile[r4 + 2][oc] * scale);
        u.w = f2bu(tile[r4 + 3][oc] * scale);
        *(ushort4*)(out + (size_t)(c0 + oc) * R + r0 + r4) = u;
    }
}

// fcw [2048][32000] fp32 -> fcwT [32000][2048] bf16; tile 256 rows x 64 cols.
__device__ __forceinline__ void job_fcw256(const float* __restrict__ in,
                                           bfu* __restrict__ out, int tx, int ty,
                                           char* lds) {
    const int r0 = ty * 256, c0 = tx * 64;
    const int t = threadIdx.x;
#pragma unroll
    for (int it = 0; it < 16; ++it) {
        int fi = it * 256 + t;
        int row = fi >> 4, c4 = (fi & 15) * 4;
        float4 v = *(const float4*)(in + (size_t)(r0 + row) * NVOC + c0 + c4);
        ushort4 u;
        u.x = f2bu(v.x); u.y = f2bu(v.y); u.z = f2bu(v.z); u.w = f2bu(v.w);
        *(ushort4*)(lds + row * 128 + ((c4 * 2) ^ (((row >> 3) & 7) << 4))) = u;
    }
    __syncthreads();
#pragma unroll
    for (int it = 0; it < 8; ++it) {
        int idx = it * 256 + t;
        int oc = idx >> 5, r8 = (idx & 31) * 8;
        bf16x8 v;
#pragma unroll
        for (int j = 0; j < 8; ++j) {
            int row = r8 + j;
            v[j] = (short)*(const bfu*)(lds + row * 128 +
                                        ((oc * 2) ^ (((row >> 3) & 7) << 4)));
        }
        *(bf16x8*)(out + (size_t)(c0 + oc) * D_EMB + r0 + r8) = v;
    }
}

__global__ __launch_bounds__(256)
void k_prep(const int* __restrict__ ids, const float* __restrict__ we,
            const float* __restrict__ pe, bfu* __restrict__ xb,
            const float* __restrict__ Wq, const float* __restrict__ Wk,
            const float* __restrict__ Wv, const float* __restrict__ projw,
            const float* __restrict__ fcw, bfu* __restrict__ WqT,
            bfu* __restrict__ WkT, bfu* __restrict__ WvT,
            bfu* __restrict__ projT, bfu* __restrict__ fcwT, float qscale) {
    __shared__ __align__(16) char lds[256 * 65 * 4];
    int b = blockIdx.x;
    if (b < 4000) {
        job_fcw256(fcw, fcwT, b % 500, b / 500, lds);
    } else if (b < 5024) {
        int bb = b - 4000;
        job_t64(projw, projT, D_EMB, D_EMB, 1.0f, bb & 31, bb >> 5, lds);
    } else if (b < 8096) {
        int bb = b - 5024;
        int which = bb >> 10;            // 0=Wq 1=Wk 2=Wv
        bb &= 1023;
        int z = bb >> 6, rem = bb & 63;
        size_t zo = (size_t)z * D_EMB * HS;
        const float* in = (which == 0) ? Wq : (which == 1) ? Wk : Wv;
        bfu* out = (which == 0) ? WqT : (which == 1) ? WkT : WvT;
        job_t64(in + zo, out + zo, D_EMB, HS, (which == 0) ? qscale : 1.0f,
                rem & 1, rem >> 1, lds);
    } else {
        int tt = b - 8096;
        const int row = ids[tt];
        const float4* wr = (const float4*)(we + (size_t)row * D_EMB);
        const float4* pr = (const float4*)(pe + (size_t)tt * D_EMB);
        bfu* xbr = xb + (size_t)tt * D_EMB;
        int i = threadIdx.x;
#pragma unroll
        for (int r = 0; r < 2; ++r, i += 256) {
            float4 a = wr[i], p = pr[i];
            ushort4 u;
            u.x = f2bu(a.x + p.x); u.y = f2bu(a.y + p.y);
            u.z = f2bu(a.z + p.z); u.w = f2bu(a.w + p.w);
            *(ushort4*)(xbr + i * 4) = u;
        }
    }
}

// ---------------------------------------------------------------------------
// bf16 transpose: in [rows][stride] -> out [cols][Tout].  Used for V -> V^T.
// ---------------------------------------------------------------------------
__global__ void k_transpose_bf(const bfu* __restrict__ in, bfu* __restrict__ out,
                               int stride, int Tout) {
    __shared__ bfu tile[64][72];
    const int r0 = blockIdx.x * 64;
    const int c0 = blockIdx.y * 64;
    const int t = threadIdx.x;
#pragma unroll
    for (int it = 0; it < 2; ++it) {
        int idx = it * 256 + t;
        int row = idx >> 3, c8 = (idx & 7) * 8;
        *(bf16x8*)&tile[row][c8] = *(const bf16x8*)(in + (size_t)(r0 + row) * stride + c0 + c8);
    }
    __syncthreads();
#pragma unroll
    for (int it = 0; it < 2; ++it) {
        int idx = it * 256 + t;
        int oc = idx >> 3, r8 = (idx & 7) * 8;
        bf16x8 v;
#pragma unroll
        for (int j = 0; j < 8; ++j) v[j] = (short)tile[r8 + j][oc];
        *(bf16x8*)(out + (size_t)(c0 + oc) * Tout + r0 + r8) = v;
    }
}

// ---------------------------------------------------------------------------
// GEMM (m97-style 128x128), involution swizzle.  EPI 1 = bf16 + bias + resid.
// ---------------------------------------------------------------------------
template <int EPI>
__global__ __launch_bounds__(256, 2)
void k_gemm_nt(const bfu* __restrict__ A, const bfu* __restrict__ Bt,
               bfu* __restrict__ Cv, const float* __restrict__ bias,
               const bfu* __restrict__ resb, int M, int N, int K) {
    __shared__ __align__(16) char smem[2 * 128 * 64 * 2];
    const int tid = threadIdx.x;
    const int w = tid >> 6, lane = tid & 63;
    const int wr = w >> 1, wc = w & 1;
    const int lr = lane & 15, lk = lane >> 4;
    const int sw = ((lk ^ (lr & 7)) << 4);
    const int mb = M >> 7;
    const int m0 = (blockIdx.x % mb) << 7;
    const int n0 = (blockIdx.x / mb) << 7;
    char* As = smem;
    char* Bs = smem + 16384;
    f32x4 acc[4][4];
#pragma unroll
    for (int i = 0; i < 4; ++i)
#pragma unroll
        for (int j = 0; j < 4; ++j) acc[i][j] = (f32x4){0.f, 0.f, 0.f, 0.f};

    const bfu* Ag = A + (size_t)m0 * K;
    const bfu* Bg = Bt + (size_t)n0 * K;

    for (int kk = 0; kk < K; kk += 64) {
        __syncthreads();
#pragma unroll
        for (int r = 0; r < 4; ++r) {
            int i = r * 256 + tid;
            int row = i >> 3, slot = (i & 7) ^ (row & 7);
            async_copy16(As + (r * 256 + w * 64) * 16,
                         Ag + (size_t)row * K + kk + slot * 8);
        }
#pragma unroll
        for (int r = 0; r < 4; ++r) {
            int i = r * 256 + tid;
            int row = i >> 3, slot = (i & 7) ^ (row & 7);
            async_copy16(Bs + (r * 256 + w * 64) * 16,
                         Bg + (size_t)row * K + kk + slot * 8);
        }
        __syncthreads();
#pragma unroll
        for (int kc = 0; kc < 2; ++kc) {
            const int so = kc ? (sw ^ 64) : sw;
            bf16x8 a[4], b[4];
#pragma unroll
            for (int mf = 0; mf < 4; ++mf)
                a[mf] = *(const bf16x8*)(As + (wr * 64 + mf * 16 + lr) * 128 + so);
#pragma unroll
            for (int nf = 0; nf < 4; ++nf)
                b[nf] = *(const bf16x8*)(Bs + (wc * 64 + nf * 16 + lr) * 128 + so);
#pragma unroll
            for (int mf = 0; mf < 4; ++mf)
#pragma unroll
                for (int nf = 0; nf < 4; ++nf)
                    acc[mf][nf] = mfma16(a[mf], b[nf], acc[mf][nf]);
        }
    }
#pragma unroll
    for (int nf = 0; nf < 4; ++nf) {
        int col = n0 + wc * 64 + nf * 16 + lr;
        float bv = (EPI >= 1) ? bias[col] : 0.0f;
#pragma unroll
        for (int mf = 0; mf < 4; ++mf) {
            int row0 = m0 + wr * 64 + mf * 16 + lk * 4;
            f32x4 v = acc[mf][nf];
#pragma unroll
            for (int j = 0; j < 4; ++j) {
                size_t idx = (size_t)(row0 + j) * N + col;
                float val = v[j] + bv;
                if (EPI == 1) val += b2f(resb[idx]);
                Cv[idx] = f2bu(val);
            }
        }
    }
}

// ---------------------------------------------------------------------------
// 256x256 BK=64 GEMM (r11 relaxed-sync schedule — the verified optimum of
// this template: ~271us vocab, MfmaUtil ~43%, 0 bank conflicts, VGPR 128).
// Six schedule variants tried (r4/r6/r7/r8/r11/r16); r11 is the plateau.
// EPI: 0=bf16 out, 2=f32 out + bias.
// ---------------------------------------------------------------------------
__device__ __forceinline__ void stage_chunk(char* sm, const bfu* A_, const bfu* B_,
                                            int K, int tt, int kind, int w,
                                            int laneRow, int laneCol) {
    char* base = sm + (size_t)(tt & 1) * 65536 + ((kind >= 2) ? 32768 : 0);
    const bfu* G = (kind >= 2) ? B_ : A_;
#pragma unroll
    for (int r = 0; r < 2; ++r) {
        int p = w * 2 + r;
        int row0 = (kind < 2) ? ((kind & 1) * 64 + (p & 7) * 8 + (p >> 3) * 128)
                              : ((kind & 1) * 32 + (p & 3) * 8 + (p >> 2) * 64);
        const char* g = (const char*)G + ((size_t)(row0 + laneRow) * K + tt * 64) * 2 + laneCol;
        async_copy16(base + row0 * 128, g);
    }
}

template <int Q>
__device__ __forceinline__ void read_A(bf16x8 (&aA)[2][4][2], const char* bufA,
                                       int wm, int lr, int sw0) {
    const char* p = bufA + ((wm * 128 + Q * 64 + lr) * 128);
#pragma unroll
    for (int mf = 0; mf < 4; ++mf) {
        aA[Q][mf][0] = *(const bf16x8*)(p + mf * 2048 + sw0);
        aA[Q][mf][1] = *(const bf16x8*)(p + mf * 2048 + (sw0 ^ 64));
    }
}

template <int Q>
__device__ __forceinline__ void read_B(bf16x8 (&bB)[2][2], const char* bufB,
                                       int wn, int lr, int sw0) {
    const char* p = bufB + ((wn * 64 + Q * 32 + lr) * 128);
#pragma unroll
    for (int nf = 0; nf < 2; ++nf) {
        bB[nf][0] = *(const bf16x8*)(p + nf * 2048 + sw0);
        bB[nf][1] = *(const bf16x8*)(p + nf * 2048 + (sw0 ^ 64));
    }
}

template <int QM, int QN>
__device__ __forceinline__ void mfma_quad(f32x4 (&acc)[8][4], bf16x8 (&aA)[2][4][2],
                                          bf16x8 (&bB)[2][2]) {
    __builtin_amdgcn_s_setprio(1);
#pragma unroll
    for (int kc = 0; kc < 2; ++kc)
#pragma unroll
        for (int mf = 0; mf < 4; ++mf)
#pragma unroll
            for (int nf = 0; nf < 2; ++nf)
                acc[QM * 4 + mf][QN * 2 + nf] =
                    mfma16(aA[QM][mf][kc], bB[nf][kc], acc[QM * 4 + mf][QN * 2 + nf]);
    __builtin_amdgcn_s_setprio(0);
}

template <int EPI>
__global__ __launch_bounds__(512, 2)
void k_gemm256(const bfu* __restrict__ A, const bfu* __restrict__ Bt,
               void* __restrict__ Cv, const float* __restrict__ bias,
               int M, int N, int K) {
    __shared__ __align__(16) char smem[2 * 65536];   // 128 KiB
    const int tid = threadIdx.x;
    const int w = tid >> 6, lane = tid & 63;
    const int wm = w >> 2, wn = w & 3;
    const int lr = lane & 15, lk = lane >> 4;
    const int sw0 = ((lk ^ (lr & 7)) << 4);
    const int laneRow = lane >> 3;
    const int laneCol = ((lane & 7) ^ (lane >> 3)) << 4;

    const int mb = M >> 8;
    const int nwgs = mb * (N >> 8);
    int bid = blockIdx.x;
    int swz = ((nwgs & 7) == 0) ? ((bid & 7) * (nwgs >> 3) + (bid >> 3)) : bid;
    const int m0 = (swz % mb) << 8;
    const int n0 = (swz / mb) << 8;

    const bfu* Ag = A + (size_t)m0 * K;
    const bfu* Bg = Bt + (size_t)n0 * K;

    f32x4 acc[8][4];
#pragma unroll
    for (int i = 0; i < 8; ++i)
#pragma unroll
        for (int j = 0; j < 4; ++j) acc[i][j] = (f32x4){0.f, 0.f, 0.f, 0.f};
    bf16x8 aA[2][4][2], bB[2][2];

    const int nkt = K >> 6;   // requires nkt >= 4

    stage_chunk(smem, Ag, Bg, K, 0, 0, w, laneRow, laneCol);
    stage_chunk(smem, Ag, Bg, K, 0, 2, w, laneRow, laneCol);
    stage_chunk(smem, Ag, Bg, K, 0, 1, w, laneRow, laneCol);
    stage_chunk(smem, Ag, Bg, K, 0, 3, w, laneRow, laneCol);
    stage_chunk(smem, Ag, Bg, K, 1, 2, w, laneRow, laneCol);
    stage_chunk(smem, Ag, Bg, K, 1, 0, w, laneRow, laneCol);
    WAIT_VM8; SB0; BARRIER;

    for (int t = 0; t < nkt - 2; ++t) {
        const char* bufA = smem + (size_t)(t & 1) * 65536;
        const char* bufB = bufA + 32768;
        read_A<0>(aA, bufA, wm, lr, sw0);
        read_B<0>(bB, bufB, wn, lr, sw0);
        stage_chunk(smem, Ag, Bg, K, t + 1, 1, w, laneRow, laneCol);
        mfma_quad<0, 0>(acc, aA, bB);
        WAIT_VM8; BARRIER;

        read_A<1>(aA, bufA, wm, lr, sw0);
        stage_chunk(smem, Ag, Bg, K, t + 1, 3, w, laneRow, laneCol);
        mfma_quad<1, 0>(acc, aA, bB);
        WAIT_VM8; BARRIER;

        read_B<1>(bB, bufB, wn, lr, sw0);
        stage_chunk(smem, Ag, Bg, K, t + 2, 2, w, laneRow, laneCol);
        mfma_quad<0, 1>(acc, aA, bB);
        WAIT_VM8; BARRIER;

        stage_chunk(smem, Ag, Bg, K, t + 2, 0, w, laneRow, laneCol);
        mfma_quad<1, 1>(acc, aA, bB);
        WAIT_VM8; BARRIER;
    }

    {   // t = nkt-2
        const int t = nkt - 2;
        const char* bufA = smem + (size_t)(t & 1) * 65536;
        const char* bufB = bufA + 32768;
        read_A<0>(aA, bufA, wm, lr, sw0);
        read_B<0>(bB, bufB, wn, lr, sw0);
        stage_chunk(smem, Ag, Bg, K, t + 1, 1, w, laneRow, laneCol);
        mfma_quad<0, 0>(acc, aA, bB);
        WAIT_VM8; BARRIER;

        read_A<1>(aA, bufA, wm, lr, sw0);
        stage_chunk(smem, Ag, Bg, K, t + 1, 3, w, laneRow, laneCol);
        mfma_quad<1, 0>(acc, aA, bB);
        WAIT_VM8; BARRIER;

        read_B<1>(bB, bufB, wn, lr, sw0);
        mfma_quad<0, 1>(acc, aA, bB);
        WAIT_VM6; BARRIER;

        mfma_quad<1, 1>(acc, aA, bB);
        WAIT_VM4; BARRIER;
    }
    {   // t = nkt-1
        const int t = nkt - 1;
        const char* bufA = smem + (size_t)(t & 1) * 65536;
        const char* bufB = bufA + 32768;
        read_A<0>(aA, bufA, wm, lr, sw0);
        read_B<0>(bB, bufB, wn, lr, sw0);
        mfma_quad<0, 0>(acc, aA, bB);
        WAIT_VM2; BARRIER;

        read_A<1>(aA, bufA, wm, lr, sw0);
        mfma_quad<1, 0>(acc, aA, bB);
        WAIT_VM0; BARRIER;

        read_B<1>(bB, bufB, wn, lr, sw0);
        mfma_quad<0, 1>(acc, aA, bB);
        mfma_quad<1, 1>(acc, aA, bB);
    }

#pragma unroll
    for (int nfg = 0; nfg < 4; ++nfg) {
        int col = n0 + wn * 64 + nfg * 16 + lr;
        float bv = (EPI == 2) ? bias[col] : 0.0f;
#pragma unroll
        for (int mfg = 0; mfg < 8; ++mfg) {
            int row0 = m0 + wm * 128 + mfg * 16 + lk * 4;
            f32x4 v = acc[mfg][nfg];
#pragma unroll
            for (int j = 0; j < 4; ++j) {
                size_t idx = (size_t)(row0 + j) * N + col;
                if (EPI == 2) ((float*)Cv)[idx] = v[j] + bv;
                else          ((bfu*)Cv)[idx] = f2bu(v[j]);
            }
        }
    }
}

// ---------------------------------------------------------------------------
// Flash attention (causal), r12 version (LDS-staged K/V, verified).
// ---------------------------------------------------------------------------
__global__ __launch_bounds__(256, 2)
void k_attn(const bfu* __restrict__ q, const bfu* __restrict__ k,
            const bfu* __restrict__ vT, bfu* __restrict__ o, int qks) {
    __shared__ __align__(16) char kvlds[2][32768];   // [buf][K 16KB | V 16KB]
    __shared__ __align__(16) bfu plds[4][16][72];
    const int w = threadIdx.x >> 6, lane = threadIdx.x & 63;
    const int lr = lane & 15, lk = lane >> 4;
    const int h = blockIdx.y;
    const int bxr = (gridDim.x - 1) - blockIdx.x;   // heavy blocks first
    const int qrow = bxr * 64 + w * 16;
    const int sw = ((lk ^ (lr & 7)) << 4);

    const int krow = lane >> 4, kslot = lane & 15;
    const int vrow = lane >> 3, vslot = lane & 7;

    bf16x8 aq[4];
#pragma unroll
    for (int kc = 0; kc < 4; ++kc)
        aq[kc] = *(const bf16x8*)(q + (size_t)(qrow + lr) * qks + h * HS + kc * 32 + lk * 8);

    f32x4 O[8];
#pragma unroll
    for (int hf = 0; hf < 8; ++hf) O[hf] = (f32x4){0.f, 0.f, 0.f, 0.f};
    float m_[4], l_[4];
#pragma unroll
    for (int j = 0; j < 4; ++j) { m_[j] = -__builtin_inff(); l_[j] = 0.f; }

    const int nst = bxr + 1;

#define STAGE_KV(st)                                                            \
    {                                                                           \
        char* bK = kvlds[(st) & 1];                                             \
        char* bV = bK + 16384;                                                  \
        const int s0_ = (st) * 64;                                              \
        _Pragma("unroll")                                                       \
        for (int j = 0; j < 4; ++j) {                                           \
            int ir = w * 4 + j;                                                 \
            int krw = ir * 4 + krow;                                            \
            int kss = (kslot & 8) | ((kslot & 7) ^ (krw & 7));                  \
            async_copy16(bK + ir * 1024,                                        \
                         k + (size_t)(s0_ + krw) * qks + h * HS + kss * 8);     \
            int vrw = ir * 8 + vrow;                                            \
            int vss = vslot ^ (vrw & 7);                                        \
            async_copy16(bV + ir * 1024,                                        \
                         vT + (size_t)(h * HS + vrw) * T_SEQ + s0_ + vss * 8);  \
        }                                                                       \
    }

    STAGE_KV(0);
    WAIT_VM0; BARRIER;

    for (int st = 0; st < nst; ++st) {
        const char* bK = kvlds[st & 1];
        const char* bV = bK + 16384;
        const int s0 = st * 64;
        if (st + 1 < nst) STAGE_KV(st + 1);

        f32x4 S[4];
#pragma unroll
        for (int nf = 0; nf < 4; ++nf) S[nf] = (f32x4){0.f, 0.f, 0.f, 0.f};
#pragma unroll
        for (int nf = 0; nf < 4; ++nf) {
            const char* kp = bK + (nf * 16 + lr) * 256;
#pragma unroll
            for (int kc = 0; kc < 4; ++kc) {
                bf16x8 bk = *(const bf16x8*)(kp + ((kc & 2) << 6) + (sw ^ ((kc & 1) << 6)));
                S[nf] = mfma16(aq[kc], bk, S[nf]);
            }
        }
        if (s0 + 63 > qrow) {
#pragma unroll
            for (int nf = 0; nf < 4; ++nf) {
                int scol = s0 + nf * 16 + lr;
#pragma unroll
                for (int j = 0; j < 4; ++j)
                    if (scol > qrow + lk * 4 + j) S[nf][j] = -1e30f;
            }
        }
        float tm[4];
#pragma unroll
        for (int j = 0; j < 4; ++j)
            tm[j] = fmaxf(fmaxf(S[0][j], S[1][j]), fmaxf(S[2][j], S[3][j]));
#pragma unroll
        for (int d = 1; d < 16; d <<= 1)
#pragma unroll
            for (int j = 0; j < 4; ++j) tm[j] = fmaxf(tm[j], __shfl_xor(tm[j], d));
        float mn[4], ts[4];
#pragma unroll
        for (int j = 0; j < 4; ++j) mn[j] = fmaxf(m_[j], tm[j]);
#pragma unroll
        for (int nf = 0; nf < 4; ++nf)
#pragma unroll
            for (int j = 0; j < 4; ++j) S[nf][j] = __expf(S[nf][j] - mn[j]);
#pragma unroll
        for (int j = 0; j < 4; ++j) ts[j] = S[0][j] + S[1][j] + S[2][j] + S[3][j];
#pragma unroll
        for (int d = 1; d < 16; d <<= 1)
#pragma unroll
            for (int j = 0; j < 4; ++j) ts[j] += __shfl_xor(ts[j], d);
#pragma unroll
        for (int nf = 0; nf < 4; ++nf)
#pragma unroll
            for (int j = 0; j < 4; ++j)
                plds[w][lk * 4 + j][nf * 16 + lr] = f2bu(S[nf][j]);
#pragma unroll
        for (int j = 0; j < 4; ++j) {
            float f = __expf(m_[j] - mn[j]);
            l_[j] = l_[j] * f + ts[j];
            m_[j] = mn[j];
#pragma unroll
            for (int hf = 0; hf < 8; ++hf) O[hf][j] *= f;
        }
        bf16x8 pa[2];
#pragma unroll
        for (int kc2 = 0; kc2 < 2; ++kc2)
            pa[kc2] = *(const bf16x8*)(&plds[w][lr][kc2 * 32 + lk * 8]);
#pragma unroll
        for (int hf = 0; hf < 8; ++hf) {
            const char* vp = bV + (hf * 16 + lr) * 128;
#pragma unroll
            for (int kc2 = 0; kc2 < 2; ++kc2) {
                bf16x8 bv = *(const bf16x8*)(vp + (sw ^ (kc2 << 6)));
                O[hf] = mfma16(pa[kc2], bv, O[hf]);
            }
        }
        WAIT_VM0; BARRIER;
    }
#undef STAGE_KV

#pragma unroll
    for (int j = 0; j < 4; ++j) {
        float inv = 1.0f / l_[j];
        size_t rbase = (size_t)(qrow + lk * 4 + j) * D_EMB + h * HS;
#pragma unroll
        for (int hf = 0; hf < 8; ++hf)
            o[rbase + hf * 16 + lr] = f2bu(O[hf][j] * inv);
    }
}

// ---------------------------------------------------------------------------
extern "C" void kernel_launch(void* const* d_in, const int* in_sizes, int n_in,
                              void* d_out, int out_size, void* d_ws, size_t ws_size,
                              hipStream_t stream) {
    const int*   ids   = (const int*)d_in[0];
    const float* we    = (const float*)d_in[1];
    const float* pe    = (const float*)d_in[2];
    const float* Wq    = (const float*)d_in[3];
    const float* Wk    = (const float*)d_in[4];
    const float* Wv    = (const float*)d_in[5];
    const float* projw = (const float*)d_in[6];
    const float* projb = (const float*)d_in[7];
    const float* fcw   = (const float*)d_in[8];
    const float* fcb   = (const float*)d_in[9];
    float* out = (float*)d_out;
    (void)in_sizes; (void)n_in; (void)out_size; (void)ws_size;

    char* ws = (char*)d_ws;
    size_t off = 0;
    bfu*   fcwT  = (bfu*)(ws + off);  off += (size_t)NVOC * D_EMB * 2;       // 131 MB
    bfu*   xb    = (bfu*)(ws + off);  off += (size_t)T_SEQ * D_EMB * 2;
    bfu*   qkvb  = (bfu*)(ws + off);  off += (size_t)T_SEQ * 3 * D_EMB * 2;  // q|k|v [T][6144]
    bfu*   vTb   = (bfu*)(ws + off);  off += (size_t)D_EMB * T_SEQ * 2;
    bfu*   WqT   = (bfu*)(ws + off);  off += (size_t)D_EMB * D_EMB * 2;      // WqT|WkT|WvT contiguous
    bfu*   WkT   = (bfu*)(ws + off);  off += (size_t)D_EMB * D_EMB * 2;
    bfu*   WvT   = (bfu*)(ws + off);  off += (size_t)D_EMB * D_EMB * 2;
    bfu*   projT = (bfu*)(ws + off);  off += (size_t)D_EMB * D_EMB * 2;
    bfu*   attnb = WqT;   // aliased after QKV GEMM
    bfu*   resb  = WvT;

    const float qscale = 0.08838834764831845f;  // 1/sqrt(HS), folded into WqT

    k_prep<<<10144, 256, 0, stream>>>(ids, we, pe, xb, Wq, Wk, Wv, projw, fcw,
                                      WqT, WkT, WvT, projT, fcwT, qscale);

    // QKV fused projection on the proven 256x256 BK=64 kernel (bf16 out)
    k_gemm256<0><<<(T_SEQ / 256) * (3 * D_EMB / 256), 512, 0, stream>>>(
        xb, WqT, qkvb, nullptr, T_SEQ, 3 * D_EMB, D_EMB);

    k_transpose_bf<<<dim3(T_SEQ / 64, D_EMB / 64), 256, 0, stream>>>(
        qkvb + 2 * D_EMB, vTb, 3 * D_EMB, T_SEQ);

    k_attn<<<dim3(T_SEQ / 64, NHEAD), 256, 0, stream>>>(qkvb, qkvb + D_EMB, vTb, attnb, 3 * D_EMB);

    k_gemm_nt<1><<<(T_SEQ / 128) * (D_EMB / 128), 256, 0, stream>>>(
        attnb, projT, resb, projb, xb, T_SEQ, D_EMB, D_EMB);

    // vocab GEMM on the proven 256x256 BK=64 kernel (f32 out + bias)
    k_gemm256<2><<<(T_SEQ / 256) * (NVOC / 256), 512, 0, stream>>>(
        resb, fcwT, out, fcb, T_SEQ, NVOC, D_EMB);
}

// Round 18
// 560.103 us; speedup vs baseline: 1.0823x; 1.0059x over previous
//
#include <hip/hip_runtime.h>

// Problem constants
#define T_SEQ 2048
#define D_EMB 2048
#define NHEAD 16
#define HS    128
#define NVOC  32000

typedef __attribute__((ext_vector_type(8))) short bf16x8;
typedef __attribute__((ext_vector_type(4))) float f32x4;
typedef unsigned short bfu;   // bf16 bits

__device__ __forceinline__ f32x4 mfma16(bf16x8 a, bf16x8 b, f32x4 c) {
    return __builtin_amdgcn_mfma_f32_16x16x32_bf16(a, b, c, 0, 0, 0);
}

// fp32 -> bf16 RNE
__device__ __forceinline__ bfu f2bu(float f) {
    unsigned int u = __float_as_uint(f);
    unsigned int r = (u + 0x7fffu + ((u >> 16) & 1u)) >> 16;
    return (bfu)r;
}
__device__ __forceinline__ float b2f(bfu r) {
    return __uint_as_float((unsigned int)r << 16);
}

// async global->LDS, 16B per lane; lds base must be wave-uniform (HW adds lane*16)
__device__ __forceinline__ void async_copy16(void* lds, const void* g) {
    __builtin_amdgcn_global_load_lds(
        (const __attribute__((address_space(1))) unsigned int*)g,
        (__attribute__((address_space(3))) unsigned int*)lds, 16, 0, 0);
}

#define SB0 __builtin_amdgcn_sched_barrier(0)
#define BARRIER __builtin_amdgcn_s_barrier()
#define WAIT_VM8   asm volatile("s_waitcnt vmcnt(8)" ::: "memory")
#define WAIT_VM6   asm volatile("s_waitcnt vmcnt(6)" ::: "memory")
#define WAIT_VM4   asm volatile("s_waitcnt vmcnt(4)" ::: "memory")
#define WAIT_VM2   asm volatile("s_waitcnt vmcnt(2)" ::: "memory")
#define WAIT_VM0   asm volatile("s_waitcnt vmcnt(0)" ::: "memory")

// ---------------------------------------------------------------------------
// job_t64: 64x64 fp32 transpose+cvt tile (256 threads).
// job_fcw256: fcw [2048][32000] fp32 -> fcwT [32000][2048] bf16,
//             256R x 64C tiles, swizzled bf16 LDS (32KB), 512B writes.
// ---------------------------------------------------------------------------
__device__ __forceinline__ void job_t64(const float* __restrict__ in,
                                        bfu* __restrict__ out, int R, int C,
                                        float scale, int tx, int ty, char* lds) {
    float (*tile)[65] = (float(*)[65])lds;
    const int r0 = ty * 64, c0 = tx * 64;
    const int t = threadIdx.x;
#pragma unroll
    for (int it = 0; it < 4; ++it) {
        int fi = it * 256 + t;
        int row = fi >> 4, c4 = (fi & 15) * 4;
        float4 v = *(const float4*)(in + (size_t)(r0 + row) * C + c0 + c4);
        tile[row][c4]     = v.x; tile[row][c4 + 1] = v.y;
        tile[row][c4 + 2] = v.z; tile[row][c4 + 3] = v.w;
    }
    __syncthreads();
#pragma unroll
    for (int it = 0; it < 4; ++it) {
        int ci = it * 256 + t;
        int oc = ci >> 4, r4 = (ci & 15) * 4;
        ushort4 u;
        u.x = f2bu(tile[r4 + 0][oc] * scale);
        u.y = f2bu(tile[r4 + 1][oc] * scale);
        u.z = f2bu(tile[r4 + 2][oc] * scale);
        u.w = f2bu(tile[r4 + 3][oc] * scale);
        *(ushort4*)(out + (size_t)(c0 + oc) * R + r0 + r4) = u;
    }
}

__device__ __forceinline__ void job_fcw256(const float* __restrict__ in,
                                           bfu* __restrict__ out, int tx, int ty,
                                           char* lds) {
    const int r0 = ty * 256, c0 = tx * 64;
    const int t = threadIdx.x;
#pragma unroll
    for (int it = 0; it < 16; ++it) {
        int fi = it * 256 + t;
        int row = fi >> 4, c4 = (fi & 15) * 4;
        float4 v = *(const float4*)(in + (size_t)(r0 + row) * NVOC + c0 + c4);
        ushort4 u;
        u.x = f2bu(v.x); u.y = f2bu(v.y); u.z = f2bu(v.z); u.w = f2bu(v.w);
        *(ushort4*)(lds + row * 128 + ((c4 * 2) ^ (((row >> 3) & 7) << 4))) = u;
    }
    __syncthreads();
#pragma unroll
    for (int it = 0; it < 8; ++it) {
        int idx = it * 256 + t;
        int oc = idx >> 5, r8 = (idx & 31) * 8;
        bf16x8 v;
#pragma unroll
        for (int j = 0; j < 8; ++j) {
            int row = r8 + j;
            v[j] = (short)*(const bfu*)(lds + row * 128 +
                                        ((oc * 2) ^ (((row >> 3) & 7) << 4)));
        }
        *(bf16x8*)(out + (size_t)(c0 + oc) * D_EMB + r0 + r8) = v;
    }
}

// ---------------------------------------------------------------------------
// k_prep: embed + projw/Wqkv transposes (fcw transpose moved into the attn
// launch as filler — it has no consumer until the final vocab GEMM).
// Blocks: [0,1024) projw, [1024,4096) Wq/Wk/Wv, [4096,6144) embed.
// ---------------------------------------------------------------------------
__global__ __launch_bounds__(256)
void k_prep(const int* __restrict__ ids, const float* __restrict__ we,
            const float* __restrict__ pe, bfu* __restrict__ xb,
            const float* __restrict__ Wq, const float* __restrict__ Wk,
            const float* __restrict__ Wv, const float* __restrict__ projw,
            bfu* __restrict__ WqT, bfu* __restrict__ WkT, bfu* __restrict__ WvT,
            bfu* __restrict__ projT, float qscale) {
    __shared__ __align__(16) char lds[64 * 65 * 4];
    int b = blockIdx.x;
    if (b < 1024) {
        job_t64(projw, projT, D_EMB, D_EMB, 1.0f, b & 31, b >> 5, lds);
    } else if (b < 4096) {
        int bb = b - 1024;
        int which = bb >> 10;            // 0=Wq 1=Wk 2=Wv
        bb &= 1023;
        int z = bb >> 6, rem = bb & 63;
        size_t zo = (size_t)z * D_EMB * HS;
        const float* in = (which == 0) ? Wq : (which == 1) ? Wk : Wv;
        bfu* out = (which == 0) ? WqT : (which == 1) ? WkT : WvT;
        job_t64(in + zo, out + zo, D_EMB, HS, (which == 0) ? qscale : 1.0f,
                rem & 1, rem >> 1, lds);
    } else {
        int tt = b - 4096;
        const int row = ids[tt];
        const float4* wr = (const float4*)(we + (size_t)row * D_EMB);
        const float4* pr = (const float4*)(pe + (size_t)tt * D_EMB);
        bfu* xbr = xb + (size_t)tt * D_EMB;
        int i = threadIdx.x;
#pragma unroll
        for (int r = 0; r < 2; ++r, i += 256) {
            float4 a = wr[i], p = pr[i];
            ushort4 u;
            u.x = f2bu(a.x + p.x); u.y = f2bu(a.y + p.y);
            u.z = f2bu(a.z + p.z); u.w = f2bu(a.w + p.w);
            *(ushort4*)(xbr + i * 4) = u;
        }
    }
}

// ---------------------------------------------------------------------------
// bf16 transpose: in [rows][stride] -> out [cols][Tout].  Used for V -> V^T.
// ---------------------------------------------------------------------------
__global__ void k_transpose_bf(const bfu* __restrict__ in, bfu* __restrict__ out,
                               int stride, int Tout) {
    __shared__ bfu tile[64][72];
    const int r0 = blockIdx.x * 64;
    const int c0 = blockIdx.y * 64;
    const int t = threadIdx.x;
#pragma unroll
    for (int it = 0; it < 2; ++it) {
        int idx = it * 256 + t;
        int row = idx >> 3, c8 = (idx & 7) * 8;
        *(bf16x8*)&tile[row][c8] = *(const bf16x8*)(in + (size_t)(r0 + row) * stride + c0 + c8);
    }
    __syncthreads();
#pragma unroll
    for (int it = 0; it < 2; ++it) {
        int idx = it * 256 + t;
        int oc = idx >> 3, r8 = (idx & 7) * 8;
        bf16x8 v;
#pragma unroll
        for (int j = 0; j < 8; ++j) v[j] = (short)tile[r8 + j][oc];
        *(bf16x8*)(out + (size_t)(c0 + oc) * Tout + r0 + r8) = v;
    }
}

// ---------------------------------------------------------------------------
// GEMM (m97-style 128x128), involution swizzle.  EPI 1 = bf16 + bias + resid.
// ---------------------------------------------------------------------------
template <int EPI>
__global__ __launch_bounds__(256, 2)
void k_gemm_nt(const bfu* __restrict__ A, const bfu* __restrict__ Bt,
               bfu* __restrict__ Cv, const float* __restrict__ bias,
               const bfu* __restrict__ resb, int M, int N, int K) {
    __shared__ __align__(16) char smem[2 * 128 * 64 * 2];
    const int tid = threadIdx.x;
    const int w = tid >> 6, lane = tid & 63;
    const int wr = w >> 1, wc = w & 1;
    const int lr = lane & 15, lk = lane >> 4;
    const int sw = ((lk ^ (lr & 7)) << 4);
    const int mb = M >> 7;
    const int m0 = (blockIdx.x % mb) << 7;
    const int n0 = (blockIdx.x / mb) << 7;
    char* As = smem;
    char* Bs = smem + 16384;
    f32x4 acc[4][4];
#pragma unroll
    for (int i = 0; i < 4; ++i)
#pragma unroll
        for (int j = 0; j < 4; ++j) acc[i][j] = (f32x4){0.f, 0.f, 0.f, 0.f};

    const bfu* Ag = A + (size_t)m0 * K;
    const bfu* Bg = Bt + (size_t)n0 * K;

    for (int kk = 0; kk < K; kk += 64) {
        __syncthreads();
#pragma unroll
        for (int r = 0; r < 4; ++r) {
            int i = r * 256 + tid;
            int row = i >> 3, slot = (i & 7) ^ (row & 7);
            async_copy16(As + (r * 256 + w * 64) * 16,
                         Ag + (size_t)row * K + kk + slot * 8);
        }
#pragma unroll
        for (int r = 0; r < 4; ++r) {
            int i = r * 256 + tid;
            int row = i >> 3, slot = (i & 7) ^ (row & 7);
            async_copy16(Bs + (r * 256 + w * 64) * 16,
                         Bg + (size_t)row * K + kk + slot * 8);
        }
        __syncthreads();
#pragma unroll
        for (int kc = 0; kc < 2; ++kc) {
            const int so = kc ? (sw ^ 64) : sw;
            bf16x8 a[4], b[4];
#pragma unroll
            for (int mf = 0; mf < 4; ++mf)
                a[mf] = *(const bf16x8*)(As + (wr * 64 + mf * 16 + lr) * 128 + so);
#pragma unroll
            for (int nf = 0; nf < 4; ++nf)
                b[nf] = *(const bf16x8*)(Bs + (wc * 64 + nf * 16 + lr) * 128 + so);
#pragma unroll
            for (int mf = 0; mf < 4; ++mf)
#pragma unroll
                for (int nf = 0; nf < 4; ++nf)
                    acc[mf][nf] = mfma16(a[mf], b[nf], acc[mf][nf]);
        }
    }
#pragma unroll
    for (int nf = 0; nf < 4; ++nf) {
        int col = n0 + wc * 64 + nf * 16 + lr;
        float bv = (EPI >= 1) ? bias[col] : 0.0f;
#pragma unroll
        for (int mf = 0; mf < 4; ++mf) {
            int row0 = m0 + wr * 64 + mf * 16 + lk * 4;
            f32x4 v = acc[mf][nf];
#pragma unroll
            for (int j = 0; j < 4; ++j) {
                size_t idx = (size_t)(row0 + j) * N + col;
                float val = v[j] + bv;
                if (EPI == 1) val += b2f(resb[idx]);
                Cv[idx] = f2bu(val);
            }
        }
    }
}

// ---------------------------------------------------------------------------
// 256x256 BK=64 GEMM (r11 relaxed-sync schedule — verified optimum of this
// template: ~270us vocab, MfmaUtil ~43%, 0 bank conflicts, VGPR 128).
// EPI: 0=bf16 out, 2=f32 out + bias.
// ---------------------------------------------------------------------------
__device__ __forceinline__ void stage_chunk(char* sm, const bfu* A_, const bfu* B_,
                                            int K, int tt, int kind, int w,
                                            int laneRow, int laneCol) {
    char* base = sm + (size_t)(tt & 1) * 65536 + ((kind >= 2) ? 32768 : 0);
    const bfu* G = (kind >= 2) ? B_ : A_;
#pragma unroll
    for (int r = 0; r < 2; ++r) {
        int p = w * 2 + r;
        int row0 = (kind < 2) ? ((kind & 1) * 64 + (p & 7) * 8 + (p >> 3) * 128)
                              : ((kind & 1) * 32 + (p & 3) * 8 + (p >> 2) * 64);
        const char* g = (const char*)G + ((size_t)(row0 + laneRow) * K + tt * 64) * 2 + laneCol;
        async_copy16(base + row0 * 128, g);
    }
}

template <int Q>
__device__ __forceinline__ void read_A(bf16x8 (&aA)[2][4][2], const char* bufA,
                                       int wm, int lr, int sw0) {
    const char* p = bufA + ((wm * 128 + Q * 64 + lr) * 128);
#pragma unroll
    for (int mf = 0; mf < 4; ++mf) {
        aA[Q][mf][0] = *(const bf16x8*)(p + mf * 2048 + sw0);
        aA[Q][mf][1] = *(const bf16x8*)(p + mf * 2048 + (sw0 ^ 64));
    }
}

template <int Q>
__device__ __forceinline__ void read_B(bf16x8 (&bB)[2][2], const char* bufB,
                                       int wn, int lr, int sw0) {
    const char* p = bufB + ((wn * 64 + Q * 32 + lr) * 128);
#pragma unroll
    for (int nf = 0; nf < 2; ++nf) {
        bB[nf][0] = *(const bf16x8*)(p + nf * 2048 + sw0);
        bB[nf][1] = *(const bf16x8*)(p + nf * 2048 + (sw0 ^ 64));
    }
}

template <int QM, int QN>
__device__ __forceinline__ void mfma_quad(f32x4 (&acc)[8][4], bf16x8 (&aA)[2][4][2],
                                          bf16x8 (&bB)[2][2]) {
    __builtin_amdgcn_s_setprio(1);
#pragma unroll
    for (int kc = 0; kc < 2; ++kc)
#pragma unroll
        for (int mf = 0; mf < 4; ++mf)
#pragma unroll
            for (int nf = 0; nf < 2; ++nf)
                acc[QM * 4 + mf][QN * 2 + nf] =
                    mfma16(aA[QM][mf][kc], bB[nf][kc], acc[QM * 4 + mf][QN * 2 + nf]);
    __builtin_amdgcn_s_setprio(0);
}

template <int EPI>
__global__ __launch_bounds__(512, 2)
void k_gemm256(const bfu* __restrict__ A, const bfu* __restrict__ Bt,
               void* __restrict__ Cv, const float* __restrict__ bias,
               int M, int N, int K) {
    __shared__ __align__(16) char smem[2 * 65536];   // 128 KiB
    const int tid = threadIdx.x;
    const int w = tid >> 6, lane = tid & 63;
    const int wm = w >> 2, wn = w & 3;
    const int lr = lane & 15, lk = lane >> 4;
    const int sw0 = ((lk ^ (lr & 7)) << 4);
    const int laneRow = lane >> 3;
    const int laneCol = ((lane & 7) ^ (lane >> 3)) << 4;

    const int mb = M >> 8;
    const int nwgs = mb * (N >> 8);
    int bid = blockIdx.x;
    int swz = ((nwgs & 7) == 0) ? ((bid & 7) * (nwgs >> 3) + (bid >> 3)) : bid;
    const int m0 = (swz % mb) << 8;
    const int n0 = (swz / mb) << 8;

    const bfu* Ag = A + (size_t)m0 * K;
    const bfu* Bg = Bt + (size_t)n0 * K;

    f32x4 acc[8][4];
#pragma unroll
    for (int i = 0; i < 8; ++i)
#pragma unroll
        for (int j = 0; j < 4; ++j) acc[i][j] = (f32x4){0.f, 0.f, 0.f, 0.f};
    bf16x8 aA[2][4][2], bB[2][2];

    const int nkt = K >> 6;   // requires nkt >= 4

    stage_chunk(smem, Ag, Bg, K, 0, 0, w, laneRow, laneCol);
    stage_chunk(smem, Ag, Bg, K, 0, 2, w, laneRow, laneCol);
    stage_chunk(smem, Ag, Bg, K, 0, 1, w, laneRow, laneCol);
    stage_chunk(smem, Ag, Bg, K, 0, 3, w, laneRow, laneCol);
    stage_chunk(smem, Ag, Bg, K, 1, 2, w, laneRow, laneCol);
    stage_chunk(smem, Ag, Bg, K, 1, 0, w, laneRow, laneCol);
    WAIT_VM8; SB0; BARRIER;

    for (int t = 0; t < nkt - 2; ++t) {
        const char* bufA = smem + (size_t)(t & 1) * 65536;
        const char* bufB = bufA + 32768;
        read_A<0>(aA, bufA, wm, lr, sw0);
        read_B<0>(bB, bufB, wn, lr, sw0);
        stage_chunk(smem, Ag, Bg, K, t + 1, 1, w, laneRow, laneCol);
        mfma_quad<0, 0>(acc, aA, bB);
        WAIT_VM8; BARRIER;

        read_A<1>(aA, bufA, wm, lr, sw0);
        stage_chunk(smem, Ag, Bg, K, t + 1, 3, w, laneRow, laneCol);
        mfma_quad<1, 0>(acc, aA, bB);
        WAIT_VM8; BARRIER;

        read_B<1>(bB, bufB, wn, lr, sw0);
        stage_chunk(smem, Ag, Bg, K, t + 2, 2, w, laneRow, laneCol);
        mfma_quad<0, 1>(acc, aA, bB);
        WAIT_VM8; BARRIER;

        stage_chunk(smem, Ag, Bg, K, t + 2, 0, w, laneRow, laneCol);
        mfma_quad<1, 1>(acc, aA, bB);
        WAIT_VM8; BARRIER;
    }

    {   // t = nkt-2
        const int t = nkt - 2;
        const char* bufA = smem + (size_t)(t & 1) * 65536;
        const char* bufB = bufA + 32768;
        read_A<0>(aA, bufA, wm, lr, sw0);
        read_B<0>(bB, bufB, wn, lr, sw0);
        stage_chunk(smem, Ag, Bg, K, t + 1, 1, w, laneRow, laneCol);
        mfma_quad<0, 0>(acc, aA, bB);
        WAIT_VM8; BARRIER;

        read_A<1>(aA, bufA, wm, lr, sw0);
        stage_chunk(smem, Ag, Bg, K, t + 1, 3, w, laneRow, laneCol);
        mfma_quad<1, 0>(acc, aA, bB);
        WAIT_VM8; BARRIER;

        read_B<1>(bB, bufB, wn, lr, sw0);
        mfma_quad<0, 1>(acc, aA, bB);
        WAIT_VM6; BARRIER;

        mfma_quad<1, 1>(acc, aA, bB);
        WAIT_VM4; BARRIER;
    }
    {   // t = nkt-1
        const int t = nkt - 1;
        const char* bufA = smem + (size_t)(t & 1) * 65536;
        const char* bufB = bufA + 32768;
        read_A<0>(aA, bufA, wm, lr, sw0);
        read_B<0>(bB, bufB, wn, lr, sw0);
        mfma_quad<0, 0>(acc, aA, bB);
        WAIT_VM2; BARRIER;

        read_A<1>(aA, bufA, wm, lr, sw0);
        mfma_quad<1, 0>(acc, aA, bB);
        WAIT_VM0; BARRIER;

        read_B<1>(bB, bufB, wn, lr, sw0);
        mfma_quad<0, 1>(acc, aA, bB);
        mfma_quad<1, 1>(acc, aA, bB);
    }

#pragma unroll
    for (int nfg = 0; nfg < 4; ++nfg) {
        int col = n0 + wn * 64 + nfg * 16 + lr;
        float bv = (EPI == 2) ? bias[col] : 0.0f;
#pragma unroll
        for (int mfg = 0; mfg < 8; ++mfg) {
            int row0 = m0 + wm * 128 + mfg * 16 + lk * 4;
            f32x4 v = acc[mfg][nfg];
#pragma unroll
            for (int j = 0; j < 4; ++j) {
                size_t idx = (size_t)(row0 + j) * N + col;
                if (EPI == 2) ((float*)Cv)[idx] = v[j] + bv;
                else          ((bfu*)Cv)[idx] = f2bu(v[j]);
            }
        }
    }
}

// ---------------------------------------------------------------------------
// Flash attention (causal), r12-verified core + fcw-transpose FILLER blocks:
// blockIdx.x >= 32 runs job_fcw256 (32KB of kvlds as scratch). attn is
// bandwidth-light (62MB K/V); the 393MB fcw stream rides on idle BW and
// would otherwise serialize in prep. Grid (32+250, NHEAD).
// ---------------------------------------------------------------------------
__global__ __launch_bounds__(256, 2)
void k_attn(const bfu* __restrict__ q, const bfu* __restrict__ k,
            const bfu* __restrict__ vT, bfu* __restrict__ o, int qks,
            const float* __restrict__ fcw, bfu* __restrict__ fcwT) {
    __shared__ __align__(16) char kvlds[2][32768];   // [buf][K 16KB | V 16KB]
    __shared__ __align__(16) bfu plds[4][16][72];
    if ((int)blockIdx.x >= 32) {
        int fb = ((int)blockIdx.x - 32) + 250 * (int)blockIdx.y;  // [0,4000)
        job_fcw256(fcw, fcwT, fb % 500, fb / 500, (char*)kvlds);
        return;
    }
    const int w = threadIdx.x >> 6, lane = threadIdx.x & 63;
    const int lr = lane & 15, lk = lane >> 4;
    const int h = blockIdx.y;
    const int bxr = 31 - (int)blockIdx.x;           // heavy blocks first
    const int qrow = bxr * 64 + w * 16;
    const int sw = ((lk ^ (lr & 7)) << 4);

    const int krow = lane >> 4, kslot = lane & 15;
    const int vrow = lane >> 3, vslot = lane & 7;

    bf16x8 aq[4];
#pragma unroll
    for (int kc = 0; kc < 4; ++kc)
        aq[kc] = *(const bf16x8*)(q + (size_t)(qrow + lr) * qks + h * HS + kc * 32 + lk * 8);

    f32x4 O[8];
#pragma unroll
    for (int hf = 0; hf < 8; ++hf) O[hf] = (f32x4){0.f, 0.f, 0.f, 0.f};
    float m_[4], l_[4];
#pragma unroll
    for (int j = 0; j < 4; ++j) { m_[j] = -__builtin_inff(); l_[j] = 0.f; }

    const int nst = bxr + 1;

#define STAGE_KV(st)                                                            \
    {                                                                           \
        char* bK = kvlds[(st) & 1];                                             \
        char* bV = bK + 16384;                                                  \
        const int s0_ = (st) * 64;                                              \
        _Pragma("unroll")                                                       \
        for (int j = 0; j < 4; ++j) {                                           \
            int ir = w * 4 + j;                                                 \
            int krw = ir * 4 + krow;                                            \
            int kss = (kslot & 8) | ((kslot & 7) ^ (krw & 7));                  \
            async_copy16(bK + ir * 1024,                                        \
                         k + (size_t)(s0_ + krw) * qks + h * HS + kss * 8);     \
            int vrw = ir * 8 + vrow;                                            \
            int vss = vslot ^ (vrw & 7);                                        \
            async_copy16(bV + ir * 1024,                                        \
                         vT + (size_t)(h * HS + vrw) * T_SEQ + s0_ + vss * 8);  \
        }                                                                       \
    }

    STAGE_KV(0);
    WAIT_VM0; BARRIER;

    for (int st = 0; st < nst; ++st) {
        const char* bK = kvlds[st & 1];
        const char* bV = bK + 16384;
        const int s0 = st * 64;
        if (st + 1 < nst) STAGE_KV(st + 1);

        f32x4 S[4];
#pragma unroll
        for (int nf = 0; nf < 4; ++nf) S[nf] = (f32x4){0.f, 0.f, 0.f, 0.f};
#pragma unroll
        for (int nf = 0; nf < 4; ++nf) {
            const char* kp = bK + (nf * 16 + lr) * 256;
#pragma unroll
            for (int kc = 0; kc < 4; ++kc) {
                bf16x8 bk = *(const bf16x8*)(kp + ((kc & 2) << 6) + (sw ^ ((kc & 1) << 6)));
                S[nf] = mfma16(aq[kc], bk, S[nf]);
            }
        }
        if (s0 + 63 > qrow) {
#pragma unroll
            for (int nf = 0; nf < 4; ++nf) {
                int scol = s0 + nf * 16 + lr;
#pragma unroll
                for (int j = 0; j < 4; ++j)
                    if (scol > qrow + lk * 4 + j) S[nf][j] = -1e30f;
            }
        }
        float tm[4];
#pragma unroll
        for (int j = 0; j < 4; ++j)
            tm[j] = fmaxf(fmaxf(S[0][j], S[1][j]), fmaxf(S[2][j], S[3][j]));
#pragma unroll
        for (int d = 1; d < 16; d <<= 1)
#pragma unroll
            for (int j = 0; j < 4; ++j) tm[j] = fmaxf(tm[j], __shfl_xor(tm[j], d));
        float mn[4], ts[4];
#pragma unroll
        for (int j = 0; j < 4; ++j) mn[j] = fmaxf(m_[j], tm[j]);
#pragma unroll
        for (int nf = 0; nf < 4; ++nf)
#pragma unroll
            for (int j = 0; j < 4; ++j) S[nf][j] = __expf(S[nf][j] - mn[j]);
#pragma unroll
        for (int j = 0; j < 4; ++j) ts[j] = S[0][j] + S[1][j] + S[2][j] + S[3][j];
#pragma unroll
        for (int d = 1; d < 16; d <<= 1)
#pragma unroll
            for (int j = 0; j < 4; ++j) ts[j] += __shfl_xor(ts[j], d);
#pragma unroll
        for (int nf = 0; nf < 4; ++nf)
#pragma unroll
            for (int j = 0; j < 4; ++j)
                plds[w][lk * 4 + j][nf * 16 + lr] = f2bu(S[nf][j]);
#pragma unroll
        for (int j = 0; j < 4; ++j) {
            float f = __expf(m_[j] - mn[j]);
            l_[j] = l_[j] * f + ts[j];
            m_[j] = mn[j];
#pragma unroll
            for (int hf = 0; hf < 8; ++hf) O[hf][j] *= f;
        }
        bf16x8 pa[2];
#pragma unroll
        for (int kc2 = 0; kc2 < 2; ++kc2)
            pa[kc2] = *(const bf16x8*)(&plds[w][lr][kc2 * 32 + lk * 8]);
#pragma unroll
        for (int hf = 0; hf < 8; ++hf) {
            const char* vp = bV + (hf * 16 + lr) * 128;
#pragma unroll
            for (int kc2 = 0; kc2 < 2; ++kc2) {
                bf16x8 bv = *(const bf16x8*)(vp + (sw ^ (kc2 << 6)));
                O[hf] = mfma16(pa[kc2], bv, O[hf]);
            }
        }
        WAIT_VM0; BARRIER;
    }
#undef STAGE_KV

#pragma unroll
    for (int j = 0; j < 4; ++j) {
        float inv = 1.0f / l_[j];
        size_t rbase = (size_t)(qrow + lk * 4 + j) * D_EMB + h * HS;
#pragma unroll
        for (int hf = 0; hf < 8; ++hf)
            o[rbase + hf * 16 + lr] = f2bu(O[hf][j] * inv);
    }
}

// ---------------------------------------------------------------------------
extern "C" void kernel_launch(void* const* d_in, const int* in_sizes, int n_in,
                              void* d_out, int out_size, void* d_ws, size_t ws_size,
                              hipStream_t stream) {
    const int*   ids   = (const int*)d_in[0];
    const float* we    = (const float*)d_in[1];
    const float* pe    = (const float*)d_in[2];
    const float* Wq    = (const float*)d_in[3];
    const float* Wk    = (const float*)d_in[4];
    const float* Wv    = (const float*)d_in[5];
    const float* projw = (const float*)d_in[6];
    const float* projb = (const float*)d_in[7];
    const float* fcw   = (const float*)d_in[8];
    const float* fcb   = (const float*)d_in[9];
    float* out = (float*)d_out;
    (void)in_sizes; (void)n_in; (void)out_size; (void)ws_size;

    char* ws = (char*)d_ws;
    size_t off = 0;
    bfu*   fcwT  = (bfu*)(ws + off);  off += (size_t)NVOC * D_EMB * 2;       // 131 MB
    bfu*   xb    = (bfu*)(ws + off);  off += (size_t)T_SEQ * D_EMB * 2;
    bfu*   qkvb  = (bfu*)(ws + off);  off += (size_t)T_SEQ * 3 * D_EMB * 2;  // q|k|v [T][6144]
    bfu*   vTb   = (bfu*)(ws + off);  off += (size_t)D_EMB * T_SEQ * 2;
    bfu*   WqT   = (bfu*)(ws + off);  off += (size_t)D_EMB * D_EMB * 2;      // WqT|WkT|WvT contiguous
    bfu*   WkT   = (bfu*)(ws + off);  off += (size_t)D_EMB * D_EMB * 2;
    bfu*   WvT   = (bfu*)(ws + off);  off += (size_t)D_EMB * D_EMB * 2;
    bfu*   projT = (bfu*)(ws + off);  off += (size_t)D_EMB * D_EMB * 2;
    bfu*   attnb = WqT;   // aliased after QKV GEMM
    bfu*   resb  = WvT;

    const float qscale = 0.08838834764831845f;  // 1/sqrt(HS), folded into WqT

    // prep (no fcw): embed + projw + Wq/Wk/Wv transposes
    k_prep<<<6144, 256, 0, stream>>>(ids, we, pe, xb, Wq, Wk, Wv, projw,
                                     WqT, WkT, WvT, projT, qscale);

    // QKV fused projection on the proven 256x256 BK=64 kernel (bf16 out)
    k_gemm256<0><<<(T_SEQ / 256) * (3 * D_EMB / 256), 512, 0, stream>>>(
        xb, WqT, qkvb, nullptr, T_SEQ, 3 * D_EMB, D_EMB);

    k_transpose_bf<<<dim3(T_SEQ / 64, D_EMB / 64), 256, 0, stream>>>(
        qkvb + 2 * D_EMB, vTb, 3 * D_EMB, T_SEQ);

    // attention (32 q-tiles) + fcw transpose (4000 filler blocks), one launch
    k_attn<<<dim3(32 + 250, NHEAD), 256, 0, stream>>>(
        qkvb, qkvb + D_EMB, vTb, attnb, 3 * D_EMB, fcw, fcwT);

    k_gemm_nt<1><<<(T_SEQ / 128) * (D_EMB / 128), 256, 0, stream>>>(
        attnb, projT, resb, projb, xb, T_SEQ, D_EMB, D_EMB);

    // vocab GEMM on the proven 256x256 BK=64 kernel (f32 out + bias)
    k_gemm256<2><<<(T_SEQ / 256) * (NVOC / 256), 512, 0, stream>>>(
        resb, fcwT, out, fcb, T_SEQ, NVOC, D_EMB);
}

// Round 19
// 554.729 us; speedup vs baseline: 1.0928x; 1.0097x over previous
//
#include <hip/hip_runtime.h>

// Problem constants
#define T_SEQ 2048
#define D_EMB 2048
#define NHEAD 16
#define HS    128
#define NVOC  32000

typedef __attribute__((ext_vector_type(8))) short bf16x8;
typedef __attribute__((ext_vector_type(4))) float f32x4;
typedef unsigned short bfu;   // bf16 bits

__device__ __forceinline__ f32x4 mfma16(bf16x8 a, bf16x8 b, f32x4 c) {
    return __builtin_amdgcn_mfma_f32_16x16x32_bf16(a, b, c, 0, 0, 0);
}

// fp32 -> bf16 RNE
__device__ __forceinline__ bfu f2bu(float f) {
    unsigned int u = __float_as_uint(f);
    unsigned int r = (u + 0x7fffu + ((u >> 16) & 1u)) >> 16;
    return (bfu)r;
}
__device__ __forceinline__ float b2f(bfu r) {
    return __uint_as_float((unsigned int)r << 16);
}

// async global->LDS, 16B per lane; lds base must be wave-uniform (HW adds lane*16)
__device__ __forceinline__ void async_copy16(void* lds, const void* g) {
    __builtin_amdgcn_global_load_lds(
        (const __attribute__((address_space(1))) unsigned int*)g,
        (__attribute__((address_space(3))) unsigned int*)lds, 16, 0, 0);
}

#define SB0 __builtin_amdgcn_sched_barrier(0)
#define BARRIER __builtin_amdgcn_s_barrier()
#define WAIT_VM8   asm volatile("s_waitcnt vmcnt(8)" ::: "memory")
#define WAIT_VM6   asm volatile("s_waitcnt vmcnt(6)" ::: "memory")
#define WAIT_VM4   asm volatile("s_waitcnt vmcnt(4)" ::: "memory")
#define WAIT_VM2   asm volatile("s_waitcnt vmcnt(2)" ::: "memory")
#define WAIT_VM0   asm volatile("s_waitcnt vmcnt(0)" ::: "memory")

// ---------------------------------------------------------------------------
// Tile workers.
// job_t64:    64x64 fp32 transpose+cvt (256 threads).
// job_t64_512: same tile with 512 threads (for filler in 512-thread launches).
// job_fcw256: fcw 256R x 64C transpose tile (256 threads, 32KB swizzled LDS).
// ---------------------------------------------------------------------------
__device__ __forceinline__ void job_t64(const float* __restrict__ in,
                                        bfu* __restrict__ out, int R, int C,
                                        float scale, int tx, int ty, char* lds) {
    float (*tile)[65] = (float(*)[65])lds;
    const int r0 = ty * 64, c0 = tx * 64;
    const int t = threadIdx.x;
#pragma unroll
    for (int it = 0; it < 4; ++it) {
        int fi = it * 256 + t;
        int row = fi >> 4, c4 = (fi & 15) * 4;
        float4 v = *(const float4*)(in + (size_t)(r0 + row) * C + c0 + c4);
        tile[row][c4]     = v.x; tile[row][c4 + 1] = v.y;
        tile[row][c4 + 2] = v.z; tile[row][c4 + 3] = v.w;
    }
    __syncthreads();
#pragma unroll
    for (int it = 0; it < 4; ++it) {
        int ci = it * 256 + t;
        int oc = ci >> 4, r4 = (ci & 15) * 4;
        ushort4 u;
        u.x = f2bu(tile[r4 + 0][oc] * scale);
        u.y = f2bu(tile[r4 + 1][oc] * scale);
        u.z = f2bu(tile[r4 + 2][oc] * scale);
        u.w = f2bu(tile[r4 + 3][oc] * scale);
        *(ushort4*)(out + (size_t)(c0 + oc) * R + r0 + r4) = u;
    }
}

__device__ __forceinline__ void job_t64_512(const float* __restrict__ in,
                                            bfu* __restrict__ out, int R, int C,
                                            float scale, int tx, int ty, char* lds) {
    float (*tile)[65] = (float(*)[65])lds;
    const int r0 = ty * 64, c0 = tx * 64;
    const int t = threadIdx.x;
#pragma unroll
    for (int it = 0; it < 2; ++it) {
        int fi = it * 512 + t;
        int row = fi >> 4, c4 = (fi & 15) * 4;
        float4 v = *(const float4*)(in + (size_t)(r0 + row) * C + c0 + c4);
        tile[row][c4]     = v.x; tile[row][c4 + 1] = v.y;
        tile[row][c4 + 2] = v.z; tile[row][c4 + 3] = v.w;
    }
    __syncthreads();
#pragma unroll
    for (int it = 0; it < 2; ++it) {
        int ci = it * 512 + t;
        int oc = ci >> 4, r4 = (ci & 15) * 4;
        ushort4 u;
        u.x = f2bu(tile[r4 + 0][oc] * scale);
        u.y = f2bu(tile[r4 + 1][oc] * scale);
        u.z = f2bu(tile[r4 + 2][oc] * scale);
        u.w = f2bu(tile[r4 + 3][oc] * scale);
        *(ushort4*)(out + (size_t)(c0 + oc) * R + r0 + r4) = u;
    }
}

__device__ __forceinline__ void job_fcw256(const float* __restrict__ in,
                                           bfu* __restrict__ out, int tx, int ty,
                                           char* lds) {
    const int r0 = ty * 256, c0 = tx * 64;
    const int t = threadIdx.x;
#pragma unroll
    for (int it = 0; it < 16; ++it) {
        int fi = it * 256 + t;
        int row = fi >> 4, c4 = (fi & 15) * 4;
        float4 v = *(const float4*)(in + (size_t)(r0 + row) * NVOC + c0 + c4);
        ushort4 u;
        u.x = f2bu(v.x); u.y = f2bu(v.y); u.z = f2bu(v.z); u.w = f2bu(v.w);
        *(ushort4*)(lds + row * 128 + ((c4 * 2) ^ (((row >> 3) & 7) << 4))) = u;
    }
    __syncthreads();
#pragma unroll
    for (int it = 0; it < 8; ++it) {
        int idx = it * 256 + t;
        int oc = idx >> 5, r8 = (idx & 31) * 8;
        bf16x8 v;
#pragma unroll
        for (int j = 0; j < 8; ++j) {
            int row = r8 + j;
            v[j] = (short)*(const bfu*)(lds + row * 128 +
                                        ((oc * 2) ^ (((row >> 3) & 7) << 4)));
        }
        *(bf16x8*)(out + (size_t)(c0 + oc) * D_EMB + r0 + r8) = v;
    }
}

// ---------------------------------------------------------------------------
// k_prep: embed + Wq/Wk/Wv transposes only (projw moved into QKV launch,
// fcw into attn launch — both are consumer-late and ride idle resources).
// Blocks: [0,3072) Wq/Wk/Wv, [3072,5120) embed.
// ---------------------------------------------------------------------------
__global__ __launch_bounds__(256)
void k_prep(const int* __restrict__ ids, const float* __restrict__ we,
            const float* __restrict__ pe, bfu* __restrict__ xb,
            const float* __restrict__ Wq, const float* __restrict__ Wk,
            const float* __restrict__ Wv,
            bfu* __restrict__ WqT, bfu* __restrict__ WkT, bfu* __restrict__ WvT,
            float qscale) {
    __shared__ __align__(16) char lds[64 * 65 * 4];
    int b = blockIdx.x;
    if (b < 3072) {
        int which = b >> 10;             // 0=Wq 1=Wk 2=Wv
        int bb = b & 1023;
        int z = bb >> 6, rem = bb & 63;
        size_t zo = (size_t)z * D_EMB * HS;
        const float* in = (which == 0) ? Wq : (which == 1) ? Wk : Wv;
        bfu* out = (which == 0) ? WqT : (which == 1) ? WkT : WvT;
        job_t64(in + zo, out + zo, D_EMB, HS, (which == 0) ? qscale : 1.0f,
                rem & 1, rem >> 1, lds);
    } else {
        int tt = b - 3072;
        const int row = ids[tt];
        const float4* wr = (const float4*)(we + (size_t)row * D_EMB);
        const float4* pr = (const float4*)(pe + (size_t)tt * D_EMB);
        bfu* xbr = xb + (size_t)tt * D_EMB;
        int i = threadIdx.x;
#pragma unroll
        for (int r = 0; r < 2; ++r, i += 256) {
            float4 a = wr[i], p = pr[i];
            ushort4 u;
            u.x = f2bu(a.x + p.x); u.y = f2bu(a.y + p.y);
            u.z = f2bu(a.z + p.z); u.w = f2bu(a.w + p.w);
            *(ushort4*)(xbr + i * 4) = u;
        }
    }
}

// ---------------------------------------------------------------------------
// bf16 transpose: in [rows][stride] -> out [cols][Tout].  Used for V -> V^T.
// ---------------------------------------------------------------------------
__global__ void k_transpose_bf(const bfu* __restrict__ in, bfu* __restrict__ out,
                               int stride, int Tout) {
    __shared__ bfu tile[64][72];
    const int r0 = blockIdx.x * 64;
    const int c0 = blockIdx.y * 64;
    const int t = threadIdx.x;
#pragma unroll
    for (int it = 0; it < 2; ++it) {
        int idx = it * 256 + t;
        int row = idx >> 3, c8 = (idx & 7) * 8;
        *(bf16x8*)&tile[row][c8] = *(const bf16x8*)(in + (size_t)(r0 + row) * stride + c0 + c8);
    }
    __syncthreads();
#pragma unroll
    for (int it = 0; it < 2; ++it) {
        int idx = it * 256 + t;
        int oc = idx >> 3, r8 = (idx & 7) * 8;
        bf16x8 v;
#pragma unroll
        for (int j = 0; j < 8; ++j) v[j] = (short)tile[r8 + j][oc];
        *(bf16x8*)(out + (size_t)(c0 + oc) * Tout + r0 + r8) = v;
    }
}

// ---------------------------------------------------------------------------
// GEMM (m97-style 128x128), involution swizzle.  EPI 1 = bf16 + bias + resid.
// ---------------------------------------------------------------------------
template <int EPI>
__global__ __launch_bounds__(256, 2)
void k_gemm_nt(const bfu* __restrict__ A, const bfu* __restrict__ Bt,
               bfu* __restrict__ Cv, const float* __restrict__ bias,
               const bfu* __restrict__ resb, int M, int N, int K) {
    __shared__ __align__(16) char smem[2 * 128 * 64 * 2];
    const int tid = threadIdx.x;
    const int w = tid >> 6, lane = tid & 63;
    const int wr = w >> 1, wc = w & 1;
    const int lr = lane & 15, lk = lane >> 4;
    const int sw = ((lk ^ (lr & 7)) << 4);
    const int mb = M >> 7;
    const int m0 = (blockIdx.x % mb) << 7;
    const int n0 = (blockIdx.x / mb) << 7;
    char* As = smem;
    char* Bs = smem + 16384;
    f32x4 acc[4][4];
#pragma unroll
    for (int i = 0; i < 4; ++i)
#pragma unroll
        for (int j = 0; j < 4; ++j) acc[i][j] = (f32x4){0.f, 0.f, 0.f, 0.f};

    const bfu* Ag = A + (size_t)m0 * K;
    const bfu* Bg = Bt + (size_t)n0 * K;

    for (int kk = 0; kk < K; kk += 64) {
        __syncthreads();
#pragma unroll
        for (int r = 0; r < 4; ++r) {
            int i = r * 256 + tid;
            int row = i >> 3, slot = (i & 7) ^ (row & 7);
            async_copy16(As + (r * 256 + w * 64) * 16,
                         Ag + (size_t)row * K + kk + slot * 8);
        }
#pragma unroll
        for (int r = 0; r < 4; ++r) {
            int i = r * 256 + tid;
            int row = i >> 3, slot = (i & 7) ^ (row & 7);
            async_copy16(Bs + (r * 256 + w * 64) * 16,
                         Bg + (size_t)row * K + kk + slot * 8);
        }
        __syncthreads();
#pragma unroll
        for (int kc = 0; kc < 2; ++kc) {
            const int so = kc ? (sw ^ 64) : sw;
            bf16x8 a[4], b[4];
#pragma unroll
            for (int mf = 0; mf < 4; ++mf)
                a[mf] = *(const bf16x8*)(As + (wr * 64 + mf * 16 + lr) * 128 + so);
#pragma unroll
            for (int nf = 0; nf < 4; ++nf)
                b[nf] = *(const bf16x8*)(Bs + (wc * 64 + nf * 16 + lr) * 128 + so);
#pragma unroll
            for (int mf = 0; mf < 4; ++mf)
#pragma unroll
                for (int nf = 0; nf < 4; ++nf)
                    acc[mf][nf] = mfma16(a[mf], b[nf], acc[mf][nf]);
        }
    }
#pragma unroll
    for (int nf = 0; nf < 4; ++nf) {
        int col = n0 + wc * 64 + nf * 16 + lr;
        float bv = (EPI >= 1) ? bias[col] : 0.0f;
#pragma unroll
        for (int mf = 0; mf < 4; ++mf) {
            int row0 = m0 + wr * 64 + mf * 16 + lk * 4;
            f32x4 v = acc[mf][nf];
#pragma unroll
            for (int j = 0; j < 4; ++j) {
                size_t idx = (size_t)(row0 + j) * N + col;
                float val = v[j] + bv;
                if (EPI == 1) val += b2f(resb[idx]);
                Cv[idx] = f2bu(val);
            }
        }
    }
}

// ---------------------------------------------------------------------------
// 256x256 BK=64 GEMM (r11 relaxed-sync schedule — verified optimum of this
// template: ~270us vocab, MfmaUtil ~43%, 0 bank conflicts, VGPR 128).
// EPI: 0=bf16 out, 2=f32 out + bias.
// FUSE_PROJW: filler blocks (>= gemm_nwgs) run the projw transpose with the
// 512-thread tile worker — fills the 64 CUs the 192-block QKV GEMM leaves idle.
// ---------------------------------------------------------------------------
__device__ __forceinline__ void stage_chunk(char* sm, const bfu* A_, const bfu* B_,
                                            int K, int tt, int kind, int w,
                                            int laneRow, int laneCol) {
    char* base = sm + (size_t)(tt & 1) * 65536 + ((kind >= 2) ? 32768 : 0);
    const bfu* G = (kind >= 2) ? B_ : A_;
#pragma unroll
    for (int r = 0; r < 2; ++r) {
        int p = w * 2 + r;
        int row0 = (kind < 2) ? ((kind & 1) * 64 + (p & 7) * 8 + (p >> 3) * 128)
                              : ((kind & 1) * 32 + (p & 3) * 8 + (p >> 2) * 64);
        const char* g = (const char*)G + ((size_t)(row0 + laneRow) * K + tt * 64) * 2 + laneCol;
        async_copy16(base + row0 * 128, g);
    }
}

template <int Q>
__device__ __forceinline__ void read_A(bf16x8 (&aA)[2][4][2], const char* bufA,
                                       int wm, int lr, int sw0) {
    const char* p = bufA + ((wm * 128 + Q * 64 + lr) * 128);
#pragma unroll
    for (int mf = 0; mf < 4; ++mf) {
        aA[Q][mf][0] = *(const bf16x8*)(p + mf * 2048 + sw0);
        aA[Q][mf][1] = *(const bf16x8*)(p + mf * 2048 + (sw0 ^ 64));
    }
}

template <int Q>
__device__ __forceinline__ void read_B(bf16x8 (&bB)[2][2], const char* bufB,
                                       int wn, int lr, int sw0) {
    const char* p = bufB + ((wn * 64 + Q * 32 + lr) * 128);
#pragma unroll
    for (int nf = 0; nf < 2; ++nf) {
        bB[nf][0] = *(const bf16x8*)(p + nf * 2048 + sw0);
        bB[nf][1] = *(const bf16x8*)(p + nf * 2048 + (sw0 ^ 64));
    }
}

template <int QM, int QN>
__device__ __forceinline__ void mfma_quad(f32x4 (&acc)[8][4], bf16x8 (&aA)[2][4][2],
                                          bf16x8 (&bB)[2][2]) {
    __builtin_amdgcn_s_setprio(1);
#pragma unroll
    for (int kc = 0; kc < 2; ++kc)
#pragma unroll
        for (int mf = 0; mf < 4; ++mf)
#pragma unroll
            for (int nf = 0; nf < 2; ++nf)
                acc[QM * 4 + mf][QN * 2 + nf] =
                    mfma16(aA[QM][mf][kc], bB[nf][kc], acc[QM * 4 + mf][QN * 2 + nf]);
    __builtin_amdgcn_s_setprio(0);
}

template <int EPI, bool FUSE_PROJW>
__global__ __launch_bounds__(512, 2)
void k_gemm256(const bfu* __restrict__ A, const bfu* __restrict__ Bt,
               void* __restrict__ Cv, const float* __restrict__ bias,
               int M, int N, int K,
               const float* __restrict__ projw, bfu* __restrict__ projT,
               int gemm_nwgs) {
    __shared__ __align__(16) char smem[2 * 65536];   // 128 KiB
    if (FUSE_PROJW && (int)blockIdx.x >= gemm_nwgs) {
        int fb = blockIdx.x - gemm_nwgs;             // [0, 1024)
        job_t64_512(projw, projT, D_EMB, D_EMB, 1.0f, fb & 31, fb >> 5, smem);
        return;
    }
    const int tid = threadIdx.x;
    const int w = tid >> 6, lane = tid & 63;
    const int wm = w >> 2, wn = w & 3;
    const int lr = lane & 15, lk = lane >> 4;
    const int sw0 = ((lk ^ (lr & 7)) << 4);
    const int laneRow = lane >> 3;
    const int laneCol = ((lane & 7) ^ (lane >> 3)) << 4;

    const int mb = M >> 8;
    const int nwgs = mb * (N >> 8);
    int bid = blockIdx.x;
    int swz = ((nwgs & 7) == 0) ? ((bid & 7) * (nwgs >> 3) + (bid >> 3)) : bid;
    const int m0 = (swz % mb) << 8;
    const int n0 = (swz / mb) << 8;

    const bfu* Ag = A + (size_t)m0 * K;
    const bfu* Bg = Bt + (size_t)n0 * K;

    f32x4 acc[8][4];
#pragma unroll
    for (int i = 0; i < 8; ++i)
#pragma unroll
        for (int j = 0; j < 4; ++j) acc[i][j] = (f32x4){0.f, 0.f, 0.f, 0.f};
    bf16x8 aA[2][4][2], bB[2][2];

    const int nkt = K >> 6;   // requires nkt >= 4

    stage_chunk(smem, Ag, Bg, K, 0, 0, w, laneRow, laneCol);
    stage_chunk(smem, Ag, Bg, K, 0, 2, w, laneRow, laneCol);
    stage_chunk(smem, Ag, Bg, K, 0, 1, w, laneRow, laneCol);
    stage_chunk(smem, Ag, Bg, K, 0, 3, w, laneRow, laneCol);
    stage_chunk(smem, Ag, Bg, K, 1, 2, w, laneRow, laneCol);
    stage_chunk(smem, Ag, Bg, K, 1, 0, w, laneRow, laneCol);
    WAIT_VM8; SB0; BARRIER;

    for (int t = 0; t < nkt - 2; ++t) {
        const char* bufA = smem + (size_t)(t & 1) * 65536;
        const char* bufB = bufA + 32768;
        read_A<0>(aA, bufA, wm, lr, sw0);
        read_B<0>(bB, bufB, wn, lr, sw0);
        stage_chunk(smem, Ag, Bg, K, t + 1, 1, w, laneRow, laneCol);
        mfma_quad<0, 0>(acc, aA, bB);
        WAIT_VM8; BARRIER;

        read_A<1>(aA, bufA, wm, lr, sw0);
        stage_chunk(smem, Ag, Bg, K, t + 1, 3, w, laneRow, laneCol);
        mfma_quad<1, 0>(acc, aA, bB);
        WAIT_VM8; BARRIER;

        read_B<1>(bB, bufB, wn, lr, sw0);
        stage_chunk(smem, Ag, Bg, K, t + 2, 2, w, laneRow, laneCol);
        mfma_quad<0, 1>(acc, aA, bB);
        WAIT_VM8; BARRIER;

        stage_chunk(smem, Ag, Bg, K, t + 2, 0, w, laneRow, laneCol);
        mfma_quad<1, 1>(acc, aA, bB);
        WAIT_VM8; BARRIER;
    }

    {   // t = nkt-2
        const int t = nkt - 2;
        const char* bufA = smem + (size_t)(t & 1) * 65536;
        const char* bufB = bufA + 32768;
        read_A<0>(aA, bufA, wm, lr, sw0);
        read_B<0>(bB, bufB, wn, lr, sw0);
        stage_chunk(smem, Ag, Bg, K, t + 1, 1, w, laneRow, laneCol);
        mfma_quad<0, 0>(acc, aA, bB);
        WAIT_VM8; BARRIER;

        read_A<1>(aA, bufA, wm, lr, sw0);
        stage_chunk(smem, Ag, Bg, K, t + 1, 3, w, laneRow, laneCol);
        mfma_quad<1, 0>(acc, aA, bB);
        WAIT_VM8; BARRIER;

        read_B<1>(bB, bufB, wn, lr, sw0);
        mfma_quad<0, 1>(acc, aA, bB);
        WAIT_VM6; BARRIER;

        mfma_quad<1, 1>(acc, aA, bB);
        WAIT_VM4; BARRIER;
    }
    {   // t = nkt-1
        const int t = nkt - 1;
        const char* bufA = smem + (size_t)(t & 1) * 65536;
        const char* bufB = bufA + 32768;
        read_A<0>(aA, bufA, wm, lr, sw0);
        read_B<0>(bB, bufB, wn, lr, sw0);
        mfma_quad<0, 0>(acc, aA, bB);
        WAIT_VM2; BARRIER;

        read_A<1>(aA, bufA, wm, lr, sw0);
        mfma_quad<1, 0>(acc, aA, bB);
        WAIT_VM0; BARRIER;

        read_B<1>(bB, bufB, wn, lr, sw0);
        mfma_quad<0, 1>(acc, aA, bB);
        mfma_quad<1, 1>(acc, aA, bB);
    }

#pragma unroll
    for (int nfg = 0; nfg < 4; ++nfg) {
        int col = n0 + wn * 64 + nfg * 16 + lr;
        float bv = (EPI == 2) ? bias[col] : 0.0f;
#pragma unroll
        for (int mfg = 0; mfg < 8; ++mfg) {
            int row0 = m0 + wm * 128 + mfg * 16 + lk * 4;
            f32x4 v = acc[mfg][nfg];
#pragma unroll
            for (int j = 0; j < 4; ++j) {
                size_t idx = (size_t)(row0 + j) * N + col;
                if (EPI == 2) ((float*)Cv)[idx] = v[j] + bv;
                else          ((bfu*)Cv)[idx] = f2bu(v[j]);
            }
        }
    }
}

// ---------------------------------------------------------------------------
// Flash attention (causal), r12-verified core + fcw-transpose FILLER blocks.
// Grid (32+250, NHEAD); filler index fb in [0,4000).
// ---------------------------------------------------------------------------
__global__ __launch_bounds__(256, 2)
void k_attn(const bfu* __restrict__ q, const bfu* __restrict__ k,
            const bfu* __restrict__ vT, bfu* __restrict__ o, int qks,
            const float* __restrict__ fcw, bfu* __restrict__ fcwT) {
    __shared__ __align__(16) char kvlds[2][32768];   // [buf][K 16KB | V 16KB]
    __shared__ __align__(16) bfu plds[4][16][72];
    if ((int)blockIdx.x >= 32) {
        int fb = ((int)blockIdx.x - 32) + 250 * (int)blockIdx.y;  // [0,4000)
        job_fcw256(fcw, fcwT, fb % 500, fb / 500, (char*)kvlds);
        return;
    }
    const int w = threadIdx.x >> 6, lane = threadIdx.x & 63;
    const int lr = lane & 15, lk = lane >> 4;
    const int h = blockIdx.y;
    const int bxr = 31 - (int)blockIdx.x;           // heavy blocks first
    const int qrow = bxr * 64 + w * 16;
    const int sw = ((lk ^ (lr & 7)) << 4);

    const int krow = lane >> 4, kslot = lane & 15;
    const int vrow = lane >> 3, vslot = lane & 7;

    bf16x8 aq[4];
#pragma unroll
    for (int kc = 0; kc < 4; ++kc)
        aq[kc] = *(const bf16x8*)(q + (size_t)(qrow + lr) * qks + h * HS + kc * 32 + lk * 8);

    f32x4 O[8];
#pragma unroll
    for (int hf = 0; hf < 8; ++hf) O[hf] = (f32x4){0.f, 0.f, 0.f, 0.f};
    float m_[4], l_[4];
#pragma unroll
    for (int j = 0; j < 4; ++j) { m_[j] = -__builtin_inff(); l_[j] = 0.f; }

    const int nst = bxr + 1;

#define STAGE_KV(st)                                                            \
    {                                                                           \
        char* bK = kvlds[(st) & 1];                                             \
        char* bV = bK + 16384;                                                  \
        const int s0_ = (st) * 64;                                              \
        _Pragma("unroll")                                                       \
        for (int j = 0; j < 4; ++j) {                                           \
            int ir = w * 4 + j;                                                 \
            int krw = ir * 4 + krow;                                            \
            int kss = (kslot & 8) | ((kslot & 7) ^ (krw & 7));                  \
            async_copy16(bK + ir * 1024,                                        \
                         k + (size_t)(s0_ + krw) * qks + h * HS + kss * 8);     \
            int vrw = ir * 8 + vrow;                                            \
            int vss = vslot ^ (vrw & 7);                                        \
            async_copy16(bV + ir * 1024,                                        \
                         vT + (size_t)(h * HS + vrw) * T_SEQ + s0_ + vss * 8);  \
        }                                                                       \
    }

    STAGE_KV(0);
    WAIT_VM0; BARRIER;

    for (int st = 0; st < nst; ++st) {
        const char* bK = kvlds[st & 1];
        const char* bV = bK + 16384;
        const int s0 = st * 64;
        if (st + 1 < nst) STAGE_KV(st + 1);

        f32x4 S[4];
#pragma unroll
        for (int nf = 0; nf < 4; ++nf) S[nf] = (f32x4){0.f, 0.f, 0.f, 0.f};
#pragma unroll
        for (int nf = 0; nf < 4; ++nf) {
            const char* kp = bK + (nf * 16 + lr) * 256;
#pragma unroll
            for (int kc = 0; kc < 4; ++kc) {
                bf16x8 bk = *(const bf16x8*)(kp + ((kc & 2) << 6) + (sw ^ ((kc & 1) << 6)));
                S[nf] = mfma16(aq[kc], bk, S[nf]);
            }
        }
        if (s0 + 63 > qrow) {
#pragma unroll
            for (int nf = 0; nf < 4; ++nf) {
                int scol = s0 + nf * 16 + lr;
#pragma unroll
                for (int j = 0; j < 4; ++j)
                    if (scol > qrow + lk * 4 + j) S[nf][j] = -1e30f;
            }
        }
        float tm[4];
#pragma unroll
        for (int j = 0; j < 4; ++j)
            tm[j] = fmaxf(fmaxf(S[0][j], S[1][j]), fmaxf(S[2][j], S[3][j]));
#pragma unroll
        for (int d = 1; d < 16; d <<= 1)
#pragma unroll
            for (int j = 0; j < 4; ++j) tm[j] = fmaxf(tm[j], __shfl_xor(tm[j], d));
        float mn[4], ts[4];
#pragma unroll
        for (int j = 0; j < 4; ++j) mn[j] = fmaxf(m_[j], tm[j]);
#pragma unroll
        for (int nf = 0; nf < 4; ++nf)
#pragma unroll
            for (int j = 0; j < 4; ++j) S[nf][j] = __expf(S[nf][j] - mn[j]);
#pragma unroll
        for (int j = 0; j < 4; ++j) ts[j] = S[0][j] + S[1][j] + S[2][j] + S[3][j];
#pragma unroll
        for (int d = 1; d < 16; d <<= 1)
#pragma unroll
            for (int j = 0; j < 4; ++j) ts[j] += __shfl_xor(ts[j], d);
#pragma unroll
        for (int nf = 0; nf < 4; ++nf)
#pragma unroll
            for (int j = 0; j < 4; ++j)
                plds[w][lk * 4 + j][nf * 16 + lr] = f2bu(S[nf][j]);
#pragma unroll
        for (int j = 0; j < 4; ++j) {
            float f = __expf(m_[j] - mn[j]);
            l_[j] = l_[j] * f + ts[j];
            m_[j] = mn[j];
#pragma unroll
            for (int hf = 0; hf < 8; ++hf) O[hf][j] *= f;
        }
        bf16x8 pa[2];
#pragma unroll
        for (int kc2 = 0; kc2 < 2; ++kc2)
            pa[kc2] = *(const bf16x8*)(&plds[w][lr][kc2 * 32 + lk * 8]);
#pragma unroll
        for (int hf = 0; hf < 8; ++hf) {
            const char* vp = bV + (hf * 16 + lr) * 128;
#pragma unroll
            for (int kc2 = 0; kc2 < 2; ++kc2) {
                bf16x8 bv = *(const bf16x8*)(vp + (sw ^ (kc2 << 6)));
                O[hf] = mfma16(pa[kc2], bv, O[hf]);
            }
        }
        WAIT_VM0; BARRIER;
    }
#undef STAGE_KV

#pragma unroll
    for (int j = 0; j < 4; ++j) {
        float inv = 1.0f / l_[j];
        size_t rbase = (size_t)(qrow + lk * 4 + j) * D_EMB + h * HS;
#pragma unroll
        for (int hf = 0; hf < 8; ++hf)
            o[rbase + hf * 16 + lr] = f2bu(O[hf][j] * inv);
    }
}

// ---------------------------------------------------------------------------
extern "C" void kernel_launch(void* const* d_in, const int* in_sizes, int n_in,
                              void* d_out, int out_size, void* d_ws, size_t ws_size,
                              hipStream_t stream) {
    const int*   ids   = (const int*)d_in[0];
    const float* we    = (const float*)d_in[1];
    const float* pe    = (const float*)d_in[2];
    const float* Wq    = (const float*)d_in[3];
    const float* Wk    = (const float*)d_in[4];
    const float* Wv    = (const float*)d_in[5];
    const float* projw = (const float*)d_in[6];
    const float* projb = (const float*)d_in[7];
    const float* fcw   = (const float*)d_in[8];
    const float* fcb   = (const float*)d_in[9];
    float* out = (float*)d_out;
    (void)in_sizes; (void)n_in; (void)out_size; (void)ws_size;

    char* ws = (char*)d_ws;
    size_t off = 0;
    bfu*   fcwT  = (bfu*)(ws + off);  off += (size_t)NVOC * D_EMB * 2;       // 131 MB
    bfu*   xb    = (bfu*)(ws + off);  off += (size_t)T_SEQ * D_EMB * 2;
    bfu*   qkvb  = (bfu*)(ws + off);  off += (size_t)T_SEQ * 3 * D_EMB * 2;  // q|k|v [T][6144]
    bfu*   vTb   = (bfu*)(ws + off);  off += (size_t)D_EMB * T_SEQ * 2;
    bfu*   WqT   = (bfu*)(ws + off);  off += (size_t)D_EMB * D_EMB * 2;      // WqT|WkT|WvT contiguous
    bfu*   WkT   = (bfu*)(ws + off);  off += (size_t)D_EMB * D_EMB * 2;
    bfu*   WvT   = (bfu*)(ws + off);  off += (size_t)D_EMB * D_EMB * 2;
    bfu*   projT = (bfu*)(ws + off);  off += (size_t)D_EMB * D_EMB * 2;
    bfu*   attnb = WqT;   // aliased after QKV GEMM
    bfu*   resb  = WvT;

    const float qscale = 0.08838834764831845f;  // 1/sqrt(HS), folded into WqT

    // prep: embed + Wq/Wk/Wv transposes only
    k_prep<<<5120, 256, 0, stream>>>(ids, we, pe, xb, Wq, Wk, Wv,
                                     WqT, WkT, WvT, qscale);

    // QKV GEMM (192 blocks) + projw transpose (1024 filler blocks), one launch
    k_gemm256<0, true><<<192 + 1024, 512, 0, stream>>>(
        xb, WqT, qkvb, nullptr, T_SEQ, 3 * D_EMB, D_EMB, projw, projT, 192);

    k_transpose_bf<<<dim3(T_SEQ / 64, D_EMB / 64), 256, 0, stream>>>(
        qkvb + 2 * D_EMB, vTb, 3 * D_EMB, T_SEQ);

    // attention (32 q-tiles) + fcw transpose (4000 filler blocks), one launch
    k_attn<<<dim3(32 + 250, NHEAD), 256, 0, stream>>>(
        qkvb, qkvb + D_EMB, vTb, attnb, 3 * D_EMB, fcw, fcwT);

    k_gemm_nt<1><<<(T_SEQ / 128) * (D_EMB / 128), 256, 0, stream>>>(
        attnb, projT, resb, projb, xb, T_SEQ, D_EMB, D_EMB);

    // vocab GEMM on the proven 256x256 BK=64 kernel (f32 out + bias)
    k_gemm256<2, false><<<(T_SEQ / 256) * (NVOC / 256), 512, 0, stream>>>(
        resb, fcwT, out, fcb, T_SEQ, NVOC, D_EMB, nullptr, nullptr, 0);
}

// Round 20
// 554.507 us; speedup vs baseline: 1.0933x; 1.0004x over previous
//
#include <hip/hip_runtime.h>

// Problem constants
#define T_SEQ 2048
#define D_EMB 2048
#define NHEAD 16
#define HS    128
#define NVOC  32000

typedef __attribute__((ext_vector_type(8))) short bf16x8;
typedef __attribute__((ext_vector_type(4))) float f32x4;
typedef unsigned short bfu;   // bf16 bits

__device__ __forceinline__ f32x4 mfma16(bf16x8 a, bf16x8 b, f32x4 c) {
    return __builtin_amdgcn_mfma_f32_16x16x32_bf16(a, b, c, 0, 0, 0);
}

// fp32 -> bf16 RNE
__device__ __forceinline__ bfu f2bu(float f) {
    unsigned int u = __float_as_uint(f);
    unsigned int r = (u + 0x7fffu + ((u >> 16) & 1u)) >> 16;
    return (bfu)r;
}
__device__ __forceinline__ float b2f(bfu r) {
    return __uint_as_float((unsigned int)r << 16);
}

// async global->LDS, 16B per lane; lds base must be wave-uniform (HW adds lane*16)
__device__ __forceinline__ void async_copy16(void* lds, const void* g) {
    __builtin_amdgcn_global_load_lds(
        (const __attribute__((address_space(1))) unsigned int*)g,
        (__attribute__((address_space(3))) unsigned int*)lds, 16, 0, 0);
}

#define SB0 __builtin_amdgcn_sched_barrier(0)
#define BARRIER __builtin_amdgcn_s_barrier()
#define WAIT_VM8   asm volatile("s_waitcnt vmcnt(8)" ::: "memory")
#define WAIT_VM6   asm volatile("s_waitcnt vmcnt(6)" ::: "memory")
#define WAIT_VM4   asm volatile("s_waitcnt vmcnt(4)" ::: "memory")
#define WAIT_VM2   asm volatile("s_waitcnt vmcnt(2)" ::: "memory")
#define WAIT_VM0   asm volatile("s_waitcnt vmcnt(0)" ::: "memory")

// ---------------------------------------------------------------------------
// Tile workers.
// ---------------------------------------------------------------------------
__device__ __forceinline__ void job_t64(const float* __restrict__ in,
                                        bfu* __restrict__ out, int R, int C,
                                        float scale, int tx, int ty, char* lds) {
    float (*tile)[65] = (float(*)[65])lds;
    const int r0 = ty * 64, c0 = tx * 64;
    const int t = threadIdx.x;
#pragma unroll
    for (int it = 0; it < 4; ++it) {
        int fi = it * 256 + t;
        int row = fi >> 4, c4 = (fi & 15) * 4;
        float4 v = *(const float4*)(in + (size_t)(r0 + row) * C + c0 + c4);
        tile[row][c4]     = v.x; tile[row][c4 + 1] = v.y;
        tile[row][c4 + 2] = v.z; tile[row][c4 + 3] = v.w;
    }
    __syncthreads();
#pragma unroll
    for (int it = 0; it < 4; ++it) {
        int ci = it * 256 + t;
        int oc = ci >> 4, r4 = (ci & 15) * 4;
        ushort4 u;
        u.x = f2bu(tile[r4 + 0][oc] * scale);
        u.y = f2bu(tile[r4 + 1][oc] * scale);
        u.z = f2bu(tile[r4 + 2][oc] * scale);
        u.w = f2bu(tile[r4 + 3][oc] * scale);
        *(ushort4*)(out + (size_t)(c0 + oc) * R + r0 + r4) = u;
    }
}

__device__ __forceinline__ void job_t64_512(const float* __restrict__ in,
                                            bfu* __restrict__ out, int R, int C,
                                            float scale, int tx, int ty, char* lds) {
    float (*tile)[65] = (float(*)[65])lds;
    const int r0 = ty * 64, c0 = tx * 64;
    const int t = threadIdx.x;
#pragma unroll
    for (int it = 0; it < 2; ++it) {
        int fi = it * 512 + t;
        int row = fi >> 4, c4 = (fi & 15) * 4;
        float4 v = *(const float4*)(in + (size_t)(r0 + row) * C + c0 + c4);
        tile[row][c4]     = v.x; tile[row][c4 + 1] = v.y;
        tile[row][c4 + 2] = v.z; tile[row][c4 + 3] = v.w;
    }
    __syncthreads();
#pragma unroll
    for (int it = 0; it < 2; ++it) {
        int ci = it * 512 + t;
        int oc = ci >> 4, r4 = (ci & 15) * 4;
        ushort4 u;
        u.x = f2bu(tile[r4 + 0][oc] * scale);
        u.y = f2bu(tile[r4 + 1][oc] * scale);
        u.z = f2bu(tile[r4 + 2][oc] * scale);
        u.w = f2bu(tile[r4 + 3][oc] * scale);
        *(ushort4*)(out + (size_t)(c0 + oc) * R + r0 + r4) = u;
    }
}

__device__ __forceinline__ void job_fcw256(const float* __restrict__ in,
                                           bfu* __restrict__ out, int tx, int ty,
                                           char* lds) {
    const int r0 = ty * 256, c0 = tx * 64;
    const int t = threadIdx.x;
#pragma unroll
    for (int it = 0; it < 16; ++it) {
        int fi = it * 256 + t;
        int row = fi >> 4, c4 = (fi & 15) * 4;
        float4 v = *(const float4*)(in + (size_t)(r0 + row) * NVOC + c0 + c4);
        ushort4 u;
        u.x = f2bu(v.x); u.y = f2bu(v.y); u.z = f2bu(v.z); u.w = f2bu(v.w);
        *(ushort4*)(lds + row * 128 + ((c4 * 2) ^ (((row >> 3) & 7) << 4))) = u;
    }
    __syncthreads();
#pragma unroll
    for (int it = 0; it < 8; ++it) {
        int idx = it * 256 + t;
        int oc = idx >> 5, r8 = (idx & 31) * 8;
        bf16x8 v;
#pragma unroll
        for (int j = 0; j < 8; ++j) {
            int row = r8 + j;
            v[j] = (short)*(const bfu*)(lds + row * 128 +
                                        ((oc * 2) ^ (((row >> 3) & 7) << 4)));
        }
        *(bf16x8*)(out + (size_t)(c0 + oc) * D_EMB + r0 + r8) = v;
    }
}

// ---------------------------------------------------------------------------
// k_prep: embed + Wq/Wk/Wv transposes.
// Blocks: [0,3072) Wq/Wk/Wv, [3072,5120) embed.
// ---------------------------------------------------------------------------
__global__ __launch_bounds__(256)
void k_prep(const int* __restrict__ ids, const float* __restrict__ we,
            const float* __restrict__ pe, bfu* __restrict__ xb,
            const float* __restrict__ Wq, const float* __restrict__ Wk,
            const float* __restrict__ Wv,
            bfu* __restrict__ WqT, bfu* __restrict__ WkT, bfu* __restrict__ WvT,
            float qscale) {
    __shared__ __align__(16) char lds[64 * 65 * 4];
    int b = blockIdx.x;
    if (b < 3072) {
        int which = b >> 10;             // 0=Wq 1=Wk 2=Wv
        int bb = b & 1023;
        int z = bb >> 6, rem = bb & 63;
        size_t zo = (size_t)z * D_EMB * HS;
        const float* in = (which == 0) ? Wq : (which == 1) ? Wk : Wv;
        bfu* out = (which == 0) ? WqT : (which == 1) ? WkT : WvT;
        job_t64(in + zo, out + zo, D_EMB, HS, (which == 0) ? qscale : 1.0f,
                rem & 1, rem >> 1, lds);
    } else {
        int tt = b - 3072;
        const int row = ids[tt];
        const float4* wr = (const float4*)(we + (size_t)row * D_EMB);
        const float4* pr = (const float4*)(pe + (size_t)tt * D_EMB);
        bfu* xbr = xb + (size_t)tt * D_EMB;
        int i = threadIdx.x;
#pragma unroll
        for (int r = 0; r < 2; ++r, i += 256) {
            float4 a = wr[i], p = pr[i];
            ushort4 u;
            u.x = f2bu(a.x + p.x); u.y = f2bu(a.y + p.y);
            u.z = f2bu(a.z + p.z); u.w = f2bu(a.w + p.w);
            *(ushort4*)(xbr + i * 4) = u;
        }
    }
}

// ---------------------------------------------------------------------------
// bf16 transpose: in [rows][stride] -> out [cols][Tout].  Used for V -> V^T.
// ---------------------------------------------------------------------------
__global__ void k_transpose_bf(const bfu* __restrict__ in, bfu* __restrict__ out,
                               int stride, int Tout) {
    __shared__ bfu tile[64][72];
    const int r0 = blockIdx.x * 64;
    const int c0 = blockIdx.y * 64;
    const int t = threadIdx.x;
#pragma unroll
    for (int it = 0; it < 2; ++it) {
        int idx = it * 256 + t;
        int row = idx >> 3, c8 = (idx & 7) * 8;
        *(bf16x8*)&tile[row][c8] = *(const bf16x8*)(in + (size_t)(r0 + row) * stride + c0 + c8);
    }
    __syncthreads();
#pragma unroll
    for (int it = 0; it < 2; ++it) {
        int idx = it * 256 + t;
        int oc = idx >> 3, r8 = (idx & 7) * 8;
        bf16x8 v;
#pragma unroll
        for (int j = 0; j < 8; ++j) v[j] = (short)tile[r8 + j][oc];
        *(bf16x8*)(out + (size_t)(c0 + oc) * Tout + r0 + r8) = v;
    }
}

// ---------------------------------------------------------------------------
// GEMM (m97-style 128x128), involution swizzle.  EPI 1 = bf16 + bias + resid.
// ---------------------------------------------------------------------------
template <int EPI>
__global__ __launch_bounds__(256, 2)
void k_gemm_nt(const bfu* __restrict__ A, const bfu* __restrict__ Bt,
               bfu* __restrict__ Cv, const float* __restrict__ bias,
               const bfu* __restrict__ resb, int M, int N, int K) {
    __shared__ __align__(16) char smem[2 * 128 * 64 * 2];
    const int tid = threadIdx.x;
    const int w = tid >> 6, lane = tid & 63;
    const int wr = w >> 1, wc = w & 1;
    const int lr = lane & 15, lk = lane >> 4;
    const int sw = ((lk ^ (lr & 7)) << 4);
    const int mb = M >> 7;
    const int m0 = (blockIdx.x % mb) << 7;
    const int n0 = (blockIdx.x / mb) << 7;
    char* As = smem;
    char* Bs = smem + 16384;
    f32x4 acc[4][4];
#pragma unroll
    for (int i = 0; i < 4; ++i)
#pragma unroll
        for (int j = 0; j < 4; ++j) acc[i][j] = (f32x4){0.f, 0.f, 0.f, 0.f};

    const bfu* Ag = A + (size_t)m0 * K;
    const bfu* Bg = Bt + (size_t)n0 * K;

    for (int kk = 0; kk < K; kk += 64) {
        __syncthreads();
#pragma unroll
        for (int r = 0; r < 4; ++r) {
            int i = r * 256 + tid;
            int row = i >> 3, slot = (i & 7) ^ (row & 7);
            async_copy16(As + (r * 256 + w * 64) * 16,
                         Ag + (size_t)row * K + kk + slot * 8);
        }
#pragma unroll
        for (int r = 0; r < 4; ++r) {
            int i = r * 256 + tid;
            int row = i >> 3, slot = (i & 7) ^ (row & 7);
            async_copy16(Bs + (r * 256 + w * 64) * 16,
                         Bg + (size_t)row * K + kk + slot * 8);
        }
        __syncthreads();
#pragma unroll
        for (int kc = 0; kc < 2; ++kc) {
            const int so = kc ? (sw ^ 64) : sw;
            bf16x8 a[4], b[4];
#pragma unroll
            for (int mf = 0; mf < 4; ++mf)
                a[mf] = *(const bf16x8*)(As + (wr * 64 + mf * 16 + lr) * 128 + so);
#pragma unroll
            for (int nf = 0; nf < 4; ++nf)
                b[nf] = *(const bf16x8*)(Bs + (wc * 64 + nf * 16 + lr) * 128 + so);
#pragma unroll
            for (int mf = 0; mf < 4; ++mf)
#pragma unroll
                for (int nf = 0; nf < 4; ++nf)
                    acc[mf][nf] = mfma16(a[mf], b[nf], acc[mf][nf]);
        }
    }
#pragma unroll
    for (int nf = 0; nf < 4; ++nf) {
        int col = n0 + wc * 64 + nf * 16 + lr;
        float bv = (EPI >= 1) ? bias[col] : 0.0f;
#pragma unroll
        for (int mf = 0; mf < 4; ++mf) {
            int row0 = m0 + wr * 64 + mf * 16 + lk * 4;
            f32x4 v = acc[mf][nf];
#pragma unroll
            for (int j = 0; j < 4; ++j) {
                size_t idx = (size_t)(row0 + j) * N + col;
                float val = v[j] + bv;
                if (EPI == 1) val += b2f(resb[idx]);
                Cv[idx] = f2bu(val);
            }
        }
    }
}

// ---------------------------------------------------------------------------
// 256x256 BK=64 GEMM — r11 relaxed base, round-20 wait reduction: 2 vm-waits
// per K-tile instead of 4 (untested cell of the schedule matrix).
// FIFO invariant at P0(t) entry: 6 outstanding = [B1(t), B0(t+1), A0(t+1)].
//  P0: issues A1(t+1) (->8), no wait.
//  P1: issues B1(t+1) (->10), vmcnt(8) retires B1(t) for P2's read.
//  P2: issues B0(t+2) (->10), no wait.
//  P3: issues A0(t+2) (->12), vmcnt(6) retires B0/A0/A1(t+1) -> invariant.
// Prologue vmcnt(6) (retires A0/B0/A1(0) since P0 no longer waits).
// Tail: nkt-2 waits {-, vm8, -, vm4}; nkt-1 waits {vm2, vm0} (r11 tail).
// WAR pairs unchanged from r11 (stage placement untouched).
// EPI: 0=bf16 out, 2=f32 out + bias. FUSE_PROJW: filler transposes projw.
// ---------------------------------------------------------------------------
__device__ __forceinline__ void stage_chunk(char* sm, const bfu* A_, const bfu* B_,
                                            int K, int tt, int kind, int w,
                                            int laneRow, int laneCol) {
    char* base = sm + (size_t)(tt & 1) * 65536 + ((kind >= 2) ? 32768 : 0);
    const bfu* G = (kind >= 2) ? B_ : A_;
#pragma unroll
    for (int r = 0; r < 2; ++r) {
        int p = w * 2 + r;
        int row0 = (kind < 2) ? ((kind & 1) * 64 + (p & 7) * 8 + (p >> 3) * 128)
                              : ((kind & 1) * 32 + (p & 3) * 8 + (p >> 2) * 64);
        const char* g = (const char*)G + ((size_t)(row0 + laneRow) * K + tt * 64) * 2 + laneCol;
        async_copy16(base + row0 * 128, g);
    }
}

template <int Q>
__device__ __forceinline__ void read_A(bf16x8 (&aA)[2][4][2], const char* bufA,
                                       int wm, int lr, int sw0) {
    const char* p = bufA + ((wm * 128 + Q * 64 + lr) * 128);
#pragma unroll
    for (int mf = 0; mf < 4; ++mf) {
        aA[Q][mf][0] = *(const bf16x8*)(p + mf * 2048 + sw0);
        aA[Q][mf][1] = *(const bf16x8*)(p + mf * 2048 + (sw0 ^ 64));
    }
}

template <int Q>
__device__ __forceinline__ void read_B(bf16x8 (&bB)[2][2], const char* bufB,
                                       int wn, int lr, int sw0) {
    const char* p = bufB + ((wn * 64 + Q * 32 + lr) * 128);
#pragma unroll
    for (int nf = 0; nf < 2; ++nf) {
        bB[nf][0] = *(const bf16x8*)(p + nf * 2048 + sw0);
        bB[nf][1] = *(const bf16x8*)(p + nf * 2048 + (sw0 ^ 64));
    }
}

template <int QM, int QN>
__device__ __forceinline__ void mfma_quad(f32x4 (&acc)[8][4], bf16x8 (&aA)[2][4][2],
                                          bf16x8 (&bB)[2][2]) {
    __builtin_amdgcn_s_setprio(1);
#pragma unroll
    for (int kc = 0; kc < 2; ++kc)
#pragma unroll
        for (int mf = 0; mf < 4; ++mf)
#pragma unroll
            for (int nf = 0; nf < 2; ++nf)
                acc[QM * 4 + mf][QN * 2 + nf] =
                    mfma16(aA[QM][mf][kc], bB[nf][kc], acc[QM * 4 + mf][QN * 2 + nf]);
    __builtin_amdgcn_s_setprio(0);
}

template <int EPI, bool FUSE_PROJW>
__global__ __launch_bounds__(512, 2)
void k_gemm256(const bfu* __restrict__ A, const bfu* __restrict__ Bt,
               void* __restrict__ Cv, const float* __restrict__ bias,
               int M, int N, int K,
               const float* __restrict__ projw, bfu* __restrict__ projT,
               int gemm_nwgs) {
    __shared__ __align__(16) char smem[2 * 65536];   // 128 KiB
    if (FUSE_PROJW && (int)blockIdx.x >= gemm_nwgs) {
        int fb = blockIdx.x - gemm_nwgs;             // [0, 1024)
        job_t64_512(projw, projT, D_EMB, D_EMB, 1.0f, fb & 31, fb >> 5, smem);
        return;
    }
    const int tid = threadIdx.x;
    const int w = tid >> 6, lane = tid & 63;
    const int wm = w >> 2, wn = w & 3;
    const int lr = lane & 15, lk = lane >> 4;
    const int sw0 = ((lk ^ (lr & 7)) << 4);
    const int laneRow = lane >> 3;
    const int laneCol = ((lane & 7) ^ (lane >> 3)) << 4;

    const int mb = M >> 8;
    const int nwgs = mb * (N >> 8);
    int bid = blockIdx.x;
    int swz = ((nwgs & 7) == 0) ? ((bid & 7) * (nwgs >> 3) + (bid >> 3)) : bid;
    const int m0 = (swz % mb) << 8;
    const int n0 = (swz / mb) << 8;

    const bfu* Ag = A + (size_t)m0 * K;
    const bfu* Bg = Bt + (size_t)n0 * K;

    f32x4 acc[8][4];
#pragma unroll
    for (int i = 0; i < 8; ++i)
#pragma unroll
        for (int j = 0; j < 4; ++j) acc[i][j] = (f32x4){0.f, 0.f, 0.f, 0.f};
    bf16x8 aA[2][4][2], bB[2][2];

    const int nkt = K >> 6;   // requires nkt >= 4

    stage_chunk(smem, Ag, Bg, K, 0, 0, w, laneRow, laneCol);
    stage_chunk(smem, Ag, Bg, K, 0, 2, w, laneRow, laneCol);
    stage_chunk(smem, Ag, Bg, K, 0, 1, w, laneRow, laneCol);
    stage_chunk(smem, Ag, Bg, K, 0, 3, w, laneRow, laneCol);
    stage_chunk(smem, Ag, Bg, K, 1, 2, w, laneRow, laneCol);
    stage_chunk(smem, Ag, Bg, K, 1, 0, w, laneRow, laneCol);
    WAIT_VM6; SB0; BARRIER;   // retires A0(0),B0(0),A1(0); keeps [B1(0),B0(1),A0(1)]

    for (int t = 0; t < nkt - 2; ++t) {
        const char* bufA = smem + (size_t)(t & 1) * 65536;
        const char* bufB = bufA + 32768;
        // P0: no vm wait
        read_A<0>(aA, bufA, wm, lr, sw0);
        read_B<0>(bB, bufB, wn, lr, sw0);
        stage_chunk(smem, Ag, Bg, K, t + 1, 1, w, laneRow, laneCol);
        mfma_quad<0, 0>(acc, aA, bB);
        BARRIER;
        // P1: vmcnt(8) retires B1(t) for P2's read
        read_A<1>(aA, bufA, wm, lr, sw0);
        stage_chunk(smem, Ag, Bg, K, t + 1, 3, w, laneRow, laneCol);
        mfma_quad<1, 0>(acc, aA, bB);
        WAIT_VM8; BARRIER;
        // P2: no vm wait
        read_B<1>(bB, bufB, wn, lr, sw0);
        stage_chunk(smem, Ag, Bg, K, t + 2, 2, w, laneRow, laneCol);
        mfma_quad<0, 1>(acc, aA, bB);
        BARRIER;
        // P3: vmcnt(6) restores the 3-chunk invariant
        stage_chunk(smem, Ag, Bg, K, t + 2, 0, w, laneRow, laneCol);
        mfma_quad<1, 1>(acc, aA, bB);
        WAIT_VM6; BARRIER;
    }

    {   // t = nkt-2: stages only A1/B1(nkt-1); waits {-, vm8, -, vm4}
        const int t = nkt - 2;
        const char* bufA = smem + (size_t)(t & 1) * 65536;
        const char* bufB = bufA + 32768;
        read_A<0>(aA, bufA, wm, lr, sw0);
        read_B<0>(bB, bufB, wn, lr, sw0);
        stage_chunk(smem, Ag, Bg, K, t + 1, 1, w, laneRow, laneCol);
        mfma_quad<0, 0>(acc, aA, bB);
        BARRIER;

        read_A<1>(aA, bufA, wm, lr, sw0);
        stage_chunk(smem, Ag, Bg, K, t + 1, 3, w, laneRow, laneCol);
        mfma_quad<1, 0>(acc, aA, bB);
        WAIT_VM8; BARRIER;

        read_B<1>(bB, bufB, wn, lr, sw0);
        mfma_quad<0, 1>(acc, aA, bB);
        BARRIER;

        mfma_quad<1, 1>(acc, aA, bB);
        WAIT_VM4; BARRIER;
    }
    {   // t = nkt-1: drain; waits {vm2, vm0}
        const int t = nkt - 1;
        const char* bufA = smem + (size_t)(t & 1) * 65536;
        const char* bufB = bufA + 32768;
        read_A<0>(aA, bufA, wm, lr, sw0);
        read_B<0>(bB, bufB, wn, lr, sw0);
        mfma_quad<0, 0>(acc, aA, bB);
        WAIT_VM2; BARRIER;

        read_A<1>(aA, bufA, wm, lr, sw0);
        mfma_quad<1, 0>(acc, aA, bB);
        WAIT_VM0; BARRIER;

        read_B<1>(bB, bufB, wn, lr, sw0);
        mfma_quad<0, 1>(acc, aA, bB);
        mfma_quad<1, 1>(acc, aA, bB);
    }

#pragma unroll
    for (int nfg = 0; nfg < 4; ++nfg) {
        int col = n0 + wn * 64 + nfg * 16 + lr;
        float bv = (EPI == 2) ? bias[col] : 0.0f;
#pragma unroll
        for (int mfg = 0; mfg < 8; ++mfg) {
            int row0 = m0 + wm * 128 + mfg * 16 + lk * 4;
            f32x4 v = acc[mfg][nfg];
#pragma unroll
            for (int j = 0; j < 4; ++j) {
                size_t idx = (size_t)(row0 + j) * N + col;
                if (EPI == 2) ((float*)Cv)[idx] = v[j] + bv;
                else          ((bfu*)Cv)[idx] = f2bu(v[j]);
            }
        }
    }
}

// ---------------------------------------------------------------------------
// Flash attention (causal), r12-verified core + fcw-transpose FILLER blocks.
// Grid (32+250, NHEAD); filler index fb in [0,4000).
// ---------------------------------------------------------------------------
__global__ __launch_bounds__(256, 2)
void k_attn(const bfu* __restrict__ q, const bfu* __restrict__ k,
            const bfu* __restrict__ vT, bfu* __restrict__ o, int qks,
            const float* __restrict__ fcw, bfu* __restrict__ fcwT) {
    __shared__ __align__(16) char kvlds[2][32768];   // [buf][K 16KB | V 16KB]
    __shared__ __align__(16) bfu plds[4][16][72];
    if ((int)blockIdx.x >= 32) {
        int fb = ((int)blockIdx.x - 32) + 250 * (int)blockIdx.y;  // [0,4000)
        job_fcw256(fcw, fcwT, fb % 500, fb / 500, (char*)kvlds);
        return;
    }
    const int w = threadIdx.x >> 6, lane = threadIdx.x & 63;
    const int lr = lane & 15, lk = lane >> 4;
    const int h = blockIdx.y;
    const int bxr = 31 - (int)blockIdx.x;           // heavy blocks first
    const int qrow = bxr * 64 + w * 16;
    const int sw = ((lk ^ (lr & 7)) << 4);

    const int krow = lane >> 4, kslot = lane & 15;
    const int vrow = lane >> 3, vslot = lane & 7;

    bf16x8 aq[4];
#pragma unroll
    for (int kc = 0; kc < 4; ++kc)
        aq[kc] = *(const bf16x8*)(q + (size_t)(qrow + lr) * qks + h * HS + kc * 32 + lk * 8);

    f32x4 O[8];
#pragma unroll
    for (int hf = 0; hf < 8; ++hf) O[hf] = (f32x4){0.f, 0.f, 0.f, 0.f};
    float m_[4], l_[4];
#pragma unroll
    for (int j = 0; j < 4; ++j) { m_[j] = -__builtin_inff(); l_[j] = 0.f; }

    const int nst = bxr + 1;

#define STAGE_KV(st)                                                            \
    {                                                                           \
        char* bK = kvlds[(st) & 1];                                             \
        char* bV = bK + 16384;                                                  \
        const int s0_ = (st) * 64;                                              \
        _Pragma("unroll")                                                       \
        for (int j = 0; j < 4; ++j) {                                           \
            int ir = w * 4 + j;                                                 \
            int krw = ir * 4 + krow;                                            \
            int kss = (kslot & 8) | ((kslot & 7) ^ (krw & 7));                  \
            async_copy16(bK + ir * 1024,                                        \
                         k + (size_t)(s0_ + krw) * qks + h * HS + kss * 8);     \
            int vrw = ir * 8 + vrow;                                            \
            int vss = vslot ^ (vrw & 7);                                        \
            async_copy16(bV + ir * 1024,                                        \
                         vT + (size_t)(h * HS + vrw) * T_SEQ + s0_ + vss * 8);  \
        }                                                                       \
    }

    STAGE_KV(0);
    WAIT_VM0; BARRIER;

    for (int st = 0; st < nst; ++st) {
        const char* bK = kvlds[st & 1];
        const char* bV = bK + 16384;
        const int s0 = st * 64;
        if (st + 1 < nst) STAGE_KV(st + 1);

        f32x4 S[4];
#pragma unroll
        for (int nf = 0; nf < 4; ++nf) S[nf] = (f32x4){0.f, 0.f, 0.f, 0.f};
#pragma unroll
        for (int nf = 0; nf < 4; ++nf) {
            const char* kp = bK + (nf * 16 + lr) * 256;
#pragma unroll
            for (int kc = 0; kc < 4; ++kc) {
                bf16x8 bk = *(const bf16x8*)(kp + ((kc & 2) << 6) + (sw ^ ((kc & 1) << 6)));
                S[nf] = mfma16(aq[kc], bk, S[nf]);
            }
        }
        if (s0 + 63 > qrow) {
#pragma unroll
            for (int nf = 0; nf < 4; ++nf) {
                int scol = s0 + nf * 16 + lr;
#pragma unroll
                for (int j = 0; j < 4; ++j)
                    if (scol > qrow + lk * 4 + j) S[nf][j] = -1e30f;
            }
        }
        float tm[4];
#pragma unroll
        for (int j = 0; j < 4; ++j)
            tm[j] = fmaxf(fmaxf(S[0][j], S[1][j]), fmaxf(S[2][j], S[3][j]));
#pragma unroll
        for (int d = 1; d < 16; d <<= 1)
#pragma unroll
            for (int j = 0; j < 4; ++j) tm[j] = fmaxf(tm[j], __shfl_xor(tm[j], d));
        float mn[4], ts[4];
#pragma unroll
        for (int j = 0; j < 4; ++j) mn[j] = fmaxf(m_[j], tm[j]);
#pragma unroll
        for (int nf = 0; nf < 4; ++nf)
#pragma unroll
            for (int j = 0; j < 4; ++j) S[nf][j] = __expf(S[nf][j] - mn[j]);
#pragma unroll
        for (int j = 0; j < 4; ++j) ts[j] = S[0][j] + S[1][j] + S[2][j] + S[3][j];
#pragma unroll
        for (int d = 1; d < 16; d <<= 1)
#pragma unroll
            for (int j = 0; j < 4; ++j) ts[j] += __shfl_xor(ts[j], d);
#pragma unroll
        for (int nf = 0; nf < 4; ++nf)
#pragma unroll
            for (int j = 0; j < 4; ++j)
                plds[w][lk * 4 + j][nf * 16 + lr] = f2bu(S[nf][j]);
#pragma unroll
        for (int j = 0; j < 4; ++j) {
            float f = __expf(m_[j] - mn[j]);
            l_[j] = l_[j] * f + ts[j];
            m_[j] = mn[j];
#pragma unroll
            for (int hf = 0; hf < 8; ++hf) O[hf][j] *= f;
        }
        bf16x8 pa[2];
#pragma unroll
        for (int kc2 = 0; kc2 < 2; ++kc2)
            pa[kc2] = *(const bf16x8*)(&plds[w][lr][kc2 * 32 + lk * 8]);
#pragma unroll
        for (int hf = 0; hf < 8; ++hf) {
            const char* vp = bV + (hf * 16 + lr) * 128;
#pragma unroll
            for (int kc2 = 0; kc2 < 2; ++kc2) {
                bf16x8 bv = *(const bf16x8*)(vp + (sw ^ (kc2 << 6)));
                O[hf] = mfma16(pa[kc2], bv, O[hf]);
            }
        }
        WAIT_VM0; BARRIER;
    }
#undef STAGE_KV

#pragma unroll
    for (int j = 0; j < 4; ++j) {
        float inv = 1.0f / l_[j];
        size_t rbase = (size_t)(qrow + lk * 4 + j) * D_EMB + h * HS;
#pragma unroll
        for (int hf = 0; hf < 8; ++hf)
            o[rbase + hf * 16 + lr] = f2bu(O[hf][j] * inv);
    }
}

// ---------------------------------------------------------------------------
extern "C" void kernel_launch(void* const* d_in, const int* in_sizes, int n_in,
                              void* d_out, int out_size, void* d_ws, size_t ws_size,
                              hipStream_t stream) {
    const int*   ids   = (const int*)d_in[0];
    const float* we    = (const float*)d_in[1];
    const float* pe    = (const float*)d_in[2];
    const float* Wq    = (const float*)d_in[3];
    const float* Wk    = (const float*)d_in[4];
    const float* Wv    = (const float*)d_in[5];
    const float* projw = (const float*)d_in[6];
    const float* projb = (const float*)d_in[7];
    const float* fcw   = (const float*)d_in[8];
    const float* fcb   = (const float*)d_in[9];
    float* out = (float*)d_out;
    (void)in_sizes; (void)n_in; (void)out_size; (void)ws_size;

    char* ws = (char*)d_ws;
    size_t off = 0;
    bfu*   fcwT  = (bfu*)(ws + off);  off += (size_t)NVOC * D_EMB * 2;       // 131 MB
    bfu*   xb    = (bfu*)(ws + off);  off += (size_t)T_SEQ * D_EMB * 2;
    bfu*   qkvb  = (bfu*)(ws + off);  off += (size_t)T_SEQ * 3 * D_EMB * 2;  // q|k|v [T][6144]
    bfu*   vTb   = (bfu*)(ws + off);  off += (size_t)D_EMB * T_SEQ * 2;
    bfu*   WqT   = (bfu*)(ws + off);  off += (size_t)D_EMB * D_EMB * 2;      // WqT|WkT|WvT contiguous
    bfu*   WkT   = (bfu*)(ws + off);  off += (size_t)D_EMB * D_EMB * 2;
    bfu*   WvT   = (bfu*)(ws + off);  off += (size_t)D_EMB * D_EMB * 2;
    bfu*   projT = (bfu*)(ws + off);  off += (size_t)D_EMB * D_EMB * 2;
    bfu*   attnb = WqT;   // aliased after QKV GEMM
    bfu*   resb  = WvT;

    const float qscale = 0.08838834764831845f;  // 1/sqrt(HS), folded into WqT

    // prep: embed + Wq/Wk/Wv transposes only
    k_prep<<<5120, 256, 0, stream>>>(ids, we, pe, xb, Wq, Wk, Wv,
                                     WqT, WkT, WvT, qscale);

    // QKV GEMM (192 blocks) + projw transpose (1024 filler blocks), one launch
    k_gemm256<0, true><<<192 + 1024, 512, 0, stream>>>(
        xb, WqT, qkvb, nullptr, T_SEQ, 3 * D_EMB, D_EMB, projw, projT, 192);

    k_transpose_bf<<<dim3(T_SEQ / 64, D_EMB / 64), 256, 0, stream>>>(
        qkvb + 2 * D_EMB, vTb, 3 * D_EMB, T_SEQ);

    // attention (32 q-tiles) + fcw transpose (4000 filler blocks), one launch
    k_attn<<<dim3(32 + 250, NHEAD), 256, 0, stream>>>(
        qkvb, qkvb + D_EMB, vTb, attnb, 3 * D_EMB, fcw, fcwT);

    k_gemm_nt<1><<<(T_SEQ / 128) * (D_EMB / 128), 256, 0, stream>>>(
        attnb, projT, resb, projb, xb, T_SEQ, D_EMB, D_EMB);

    // vocab GEMM (f32 out + bias)
    k_gemm256<2, false><<<(T_SEQ / 256) * (NVOC / 256), 512, 0, stream>>>(
        resb, fcwT, out, fcb, T_SEQ, NVOC, D_EMB, nullptr, nullptr, 0);
}